// Round 12
// baseline (521.306 us; speedup 1.0000x reference)
//
#include <hip/hip_runtime.h>

// ---------------------------------------------------------------------------
// GeoRegionSampler: restructured pipeline
//   X = [bilinear_fea | pts] (bf16, padded 1026->1056)
//   Wcomb = Wa1 @ Wd ; Z1 = X @ Wcomb^T (bf16 out); Z2 = X[fi] @ Wa2^T (fp32)
//   h = relu(Z1[idx]-Z1[fi]+Z2+czero) -> LN -> mean_k (wave-per-q, DPP)
//   final MLP: MFMA GEMMs + K-split reduce.
// R16 (this round): 11 dispatches.
//   R15 post-mortem: noinline + bf16-Z1 worked (538->512, absmax
//   unchanged). Remaining gap vs ~190us HBM floor = dispatch boundaries
//   + fps leaks. This round: D1(bilinear ~110MB stream) and D2(prep
//   ~42MB stream) were serial but independent -> merged into ONE
//   input_prep dispatch (prep rides bilinear's HBM shadow; one fewer
//   boundary). fps0 rebalanced: [0,32) mega-D1, [32,64) wcomb, [64,128)
//   Z1 (42us chain < ~55us GEMM, hidden). LDS: prep paths overlay
//   bilinear's 74KB fmS (per-block exclusive paths).
//   Carried: noinline fps/knn cores, bf16 Z1, fi-indirect Z2, wave-per-q
//   DPP epilogue, XCD-bijective remap, fp32 mlp_mfma.
// ---------------------------------------------------------------------------

typedef float f32x4 __attribute__((ext_vector_type(4)));
typedef short bf16x8 __attribute__((ext_vector_type(8)));
typedef unsigned short u16;
typedef u16 u16x4 __attribute__((ext_vector_type(4)));
typedef unsigned int u32;
typedef u32 u32x4 __attribute__((ext_vector_type(4)));
typedef unsigned long long u64;

typedef const void __attribute__((address_space(1)))* gvp;
typedef void __attribute__((address_space(3)))* svp;

__device__ __forceinline__ u16 f2bf(float f) {
  union { float f; u32 u; } x; x.f = f;
  u32 r = x.u + 0x7fffu + ((x.u >> 16) & 1u);
  return (u16)(r >> 16);
}

__device__ __forceinline__ float bf2f(u16 h) {
  union { u32 u; float f; } x; x.u = ((u32)h) << 16;
  return x.f;
}

#define KP 1056   // padded Dp (1026 -> 33*32)
#define NP0 1152  // padded N for weight-combine GEMM (9*128)

// ---- DPP cross-lane helpers (VALU pipe) -----------------------------------
__device__ __forceinline__ float rl_f(float v, int lane) {
  return __int_as_float(__builtin_amdgcn_readlane(__float_as_int(v), lane));
}

template <int CTRL>
__device__ __forceinline__ float dpp_fmax(float v) {
  float o = __int_as_float(__builtin_amdgcn_update_dpp(
      (int)0xff800000 /* -inf */, __float_as_int(v), CTRL, 0xf, 0xf, false));
  return fmaxf(v, o);
}

template <int CTRL>
__device__ __forceinline__ float dpp_fmin(float v) {
  float o = __int_as_float(__builtin_amdgcn_update_dpp(
      0x7f800000 /* +inf */, __float_as_int(v), CTRL, 0xf, 0xf, false));
  return fminf(v, o);
}

template <int CTRL>
__device__ __forceinline__ float dpp_add(float v) {
  float o = __int_as_float(__builtin_amdgcn_update_dpp(
      0, __float_as_int(v), CTRL, 0xf, 0xf, false));
  return v + o;
}

__device__ __forceinline__ float wave_fmax63(float v) {
  v = dpp_fmax<0x111>(v);
  v = dpp_fmax<0x112>(v);
  v = dpp_fmax<0x114>(v);
  v = dpp_fmax<0x118>(v);
  v = dpp_fmax<0x142>(v);
  v = dpp_fmax<0x143>(v);
  return rl_f(v, 63);
}

__device__ __forceinline__ float wave_fmin63(float v) {
  v = dpp_fmin<0x111>(v);
  v = dpp_fmin<0x112>(v);
  v = dpp_fmin<0x114>(v);
  v = dpp_fmin<0x118>(v);
  v = dpp_fmin<0x142>(v);
  v = dpp_fmin<0x143>(v);
  return rl_f(v, 63);
}

__device__ __forceinline__ float wave_sum63(float v) {
  v = dpp_add<0x111>(v);
  v = dpp_add<0x112>(v);
  v = dpp_add<0x114>(v);
  v = dpp_add<0x118>(v);
  v = dpp_add<0x142>(v);
  v = dpp_add<0x143>(v);
  return v;
}

// ---------------- FPS core: one wave per batch, bit-exact -------------------
// Resumable [s0,s1); dist/far state spilled as raw fp32 bits (exact).
// Emits fi AND npts (coords copied bit-exact from pts) for its own range.
// noinline: keeps this path's regalloc out of the host GEMM kernel's body.
template <int PPL, int HS>
__device__ __attribute__((noinline)) void fps_core(
    const float* __restrict__ pts, int* __restrict__ fi,
    float* __restrict__ npts,
    int Np, int S, int b, int lane, int s0, int s1,
    float* __restrict__ dsave, int* __restrict__ fsave) {
  #pragma clang fp contract(off)
  float px[PPL], py[PPL], dist[PPL];
  #pragma unroll
  for (int j = 0; j < PPL; ++j) {
    int n = j * 64 + lane;
    px[j] = pts[((size_t)b * Np + n) * 2];
    py[j] = pts[((size_t)b * Np + n) * 2 + 1];
  }
  int far; float cx, cy;
  if (s0 == 0) {
    #pragma unroll
    for (int j = 0; j < PPL; ++j) dist[j] = 1e10f;
    far = 0;
    cx = rl_f(px[0], 0);
    cy = rl_f(py[0], 0);
  } else {
    #pragma unroll
    for (int j = 0; j < PPL; ++j) dist[j] = dsave[(size_t)b * Np + j * 64 + lane];
    far = fsave[b];
    cx = pts[((size_t)b * Np + far) * 2];
    cy = pts[((size_t)b * Np + far) * 2 + 1];
  }
  int hist[HS];
  #pragma unroll
  for (int h = 0; h < HS; ++h) hist[h] = 0;
  for (int s = s0; s < s1; ++s) {
    #pragma unroll
    for (int h = 0; h < HS; ++h)
      if ((s >> 6) == h && (s & 63) == lane) hist[h] = far;
    float bv = -1.f; int bi = 0; float bx = 0.f, by = 0.f;
    #pragma unroll
    for (int j = 0; j < PPL; ++j) {
      float dx = px[j] - cx, dy = py[j] - cy;
      float d = dx * dx + dy * dy;
      float nd = fminf(dist[j], d);
      dist[j] = nd;
      if (nd > bv) { bv = nd; bi = j * 64 + lane; bx = px[j]; by = py[j]; }
    }
    float smax = wave_fmax63(bv);
    u64 mask = __ballot(bv == smax);
    int L = __builtin_ctzll(mask);
    int fidx = __builtin_amdgcn_readlane(bi, L);
    float fx = rl_f(bx, L), fy = rl_f(by, L);
    u64 rest = mask & (mask - 1);
    if (__builtin_expect(rest != 0, 0)) {
      // rare: multiple lanes hold the max value -> exact min-index tiebreak
      while (rest) {
        int L2 = __builtin_ctzll(rest);
        int c = __builtin_amdgcn_readlane(bi, L2);
        if (c < fidx) {
          fidx = c; fx = rl_f(bx, L2); fy = rl_f(by, L2);
        }
        rest &= rest - 1;
      }
    }
    far = fidx; cx = fx; cy = fy;
  }
  if (s1 < S) {
    #pragma unroll
    for (int j = 0; j < PPL; ++j) dsave[(size_t)b * Np + j * 64 + lane] = dist[j];
    if (lane == 0) fsave[b] = far;
  }
  #pragma unroll
  for (int h = 0; h < HS; ++h) {
    int s = h * 64 + lane;
    if (s >= s0 && s < s1) {
      int hv = hist[h];
      fi[b * S + s] = hv;
      npts[(size_t)(b * S + s) * 2]     = pts[((size_t)b * Np + hv) * 2];
      npts[(size_t)(b * S + s) * 2 + 1] = pts[((size_t)b * Np + hv) * 2 + 1];
    }
  }
}

// ---------------- kNN core: one wave per q, bit-exact -----------------------
template <int PPL>
__device__ __attribute__((noinline)) void knn_core(
    const float* __restrict__ qpts,
    const float* __restrict__ rpts,
    int* __restrict__ idxK, int Np, int S, int q, int lane) {
  #pragma clang fp contract(off)
  int b = q / S;
  float ax = qpts[(size_t)q * 2], ay = qpts[(size_t)q * 2 + 1];
  float a2 = ax * ax + ay * ay;
  float d2[PPL];
  #pragma unroll
  for (int j = 0; j < PPL; ++j) {
    int n = j * 64 + lane;
    float bx = rpts[((size_t)b * Np + n) * 2];
    float by = rpts[((size_t)b * Np + n) * 2 + 1];
    float b2 = bx * bx + by * by;
    float dot = ax * bx + ay * by;
    float t = a2 + b2;
    float m2 = 2.f * dot;
    d2[j] = t - m2;
  }
  int kreg = 0;
  for (int k = 0; k < 24; ++k) {
    float bv = 3.4e38f; int bi = 1 << 30;
    #pragma unroll
    for (int j = 0; j < PPL; ++j)
      if (d2[j] < bv) { bv = d2[j]; bi = j * 64 + lane; }
    float smin = wave_fmin63(bv);
    u64 mask = __ballot(bv == smin);
    int L = __builtin_ctzll(mask);
    int bs = __builtin_amdgcn_readlane(bi, L);
    u64 rest = mask & (mask - 1);
    if (__builtin_expect(rest != 0, 0)) {
      while (rest) {
        int L2 = __builtin_ctzll(rest);
        int c = __builtin_amdgcn_readlane(bi, L2);
        if (c < bs) bs = c;
        rest &= rest - 1;
      }
    }
    if (lane == k) kreg = bs;
    #pragma unroll
    for (int j = 0; j < PPL; ++j)
      if (j * 64 + lane == bs) d2[j] = 3.4e38f;
  }
  if (lane < 24) idxK[(size_t)q * 24 + lane] = kreg;
}

// ---------------- GEMM tile body (shared by all MFMA GEMMs) -----------------
// IND: A rows indexed via find[] (q -> b*iNp + find[q]); C rows stay direct.
// LDS: both-sides XOR swizzle on 16B slots (linear dest for global_load_lds).
template <int BF16OUT, int IND>
__device__ __forceinline__ void gemm_tile_body(const u16* __restrict__ A,
                                               const u16* __restrict__ Bt,
                                               void* __restrict__ Cout,
                                               int K, int ldc, int nvalid,
                                               int m0, int n0,
                                               const int* __restrict__ find,
                                               int iNp, int iS,
                                               u16* __restrict__ As,
                                               u16* __restrict__ Bs) {
  const int tid = threadIdx.x;
  const int lane = tid & 63;
  const int wv = tid >> 6;
  const int wm = (wv >> 1) * 64;
  const int wn = (wv & 1) * 64;

  f32x4 acc[4][4];
  #pragma unroll
  for (int i = 0; i < 4; ++i)
    #pragma unroll
    for (int j = 0; j < 4; ++j)
      #pragma unroll
      for (int c = 0; c < 4; ++c) acc[i][j][c] = 0.f;

  const int ch0 = wv * 2;
  const int rin = lane >> 2;
  const int slot = lane & 3;
  const int cin = (slot ^ (rin & 3) ^ ((rin >> 2) & 3)) * 8;  // pre-swizzled src col

  size_t aro[2];
  #pragma unroll
  for (int i = 0; i < 2; ++i) {
    const int row = (ch0 + i) * 16 + rin;
    if (IND) {
      const int q = m0 + row;
      aro[i] = (size_t)(q / iS) * iNp + find[q];
    } else {
      aro[i] = (size_t)(m0 + row);
    }
  }

  for (int k0 = 0; k0 < K; k0 += 32) {
    #pragma unroll
    for (int i = 0; i < 2; ++i) {
      const int ch = ch0 + i;
      const int row = ch * 16 + rin;
      const u16* ga = A + aro[i] * K + (k0 + cin);
      const u16* gb = Bt + (size_t)(n0 + row) * K + (k0 + cin);
      __builtin_amdgcn_global_load_lds((gvp)ga, (svp)(As + ch * 512), 16, 0, 0);
      __builtin_amdgcn_global_load_lds((gvp)gb, (svp)(Bs + ch * 512), 16, 0, 0);
    }
    __syncthreads();
    const int rf = lane & 15;
    const int quad = lane >> 4;
    const int qs = (quad ^ (rf & 3) ^ ((rf >> 2) & 3)) * 8;  // swizzled read slot
    bf16x8 af[4], bfv[4];
    #pragma unroll
    for (int mi = 0; mi < 4; ++mi)
      af[mi] = *(const bf16x8*)(As + (wm + mi * 16 + rf) * 32 + qs);
    #pragma unroll
    for (int ni = 0; ni < 4; ++ni)
      bfv[ni] = *(const bf16x8*)(Bs + (wn + ni * 16 + rf) * 32 + qs);
    #pragma unroll
    for (int mi = 0; mi < 4; ++mi)
      #pragma unroll
      for (int ni = 0; ni < 4; ++ni)
        acc[mi][ni] = __builtin_amdgcn_mfma_f32_16x16x32_bf16(af[mi], bfv[ni], acc[mi][ni], 0, 0, 0);
    __syncthreads();
  }

  const int rq = (lane >> 4) * 4;
  const int cf = lane & 15;
  #pragma unroll
  for (int mi = 0; mi < 4; ++mi) {
    #pragma unroll
    for (int ni = 0; ni < 4; ++ni) {
      const int col = n0 + wn + ni * 16 + cf;
      #pragma unroll
      for (int r = 0; r < 4; ++r) {
        const int row = m0 + wm + mi * 16 + rq + r;
        const float v = acc[mi][ni][r];
        if (BF16OUT) {
          if (col < nvalid) ((u16*)Cout)[(size_t)row * ldc + col] = f2bf(v);
        } else {
          ((float*)Cout)[(size_t)row * ldc + col] = v;
        }
      }
    }
  }
}

// ------- mega input-prep: bilinear + wdT + waggcz + fps0 [0,32) -------------
// 1D grid 5456 blocks:
//   [0,8)        fps0 [0,32)
//   [8,1032)     bilinear (i-8: ct = i&31, b = i>>5)
//   [1032,3408)  wd_transpose (i-1032: z = i/1188, r = i%1188)
//   [3408,5456)  wagg convert + czero (i-3408: stage = i>>10, c = i&1023)
// LDS: bilinear's 74KB fmS is the block max; other paths overlay it.
__global__ __launch_bounds__(256, 2) void input_prep_kernel(
    const float* __restrict__ fmap, const float* __restrict__ pts,
    u16* __restrict__ X,
    const float* __restrict__ Wd, u16* __restrict__ WdT,
    const float* __restrict__ Wagg, const float* __restrict__ bdiff,
    const float* __restrict__ bagg,
    u16* __restrict__ Wa1, u16* __restrict__ Wa2, float* __restrict__ czero,
    int* __restrict__ fi0, float* __restrict__ npts0,
    float* __restrict__ fdist, int* __restrict__ ffar) {
  __shared__ float fmS[32][580];
  const int bid = blockIdx.x;
  const int t = threadIdx.x;
  const int lane = t & 63, wv = t >> 6;

  if (bid < 8) {
    fps_core<8, 2>(pts, fi0, npts0, 512, 128, bid * 4 + wv, lane, 0, 32, fdist, ffar);
    return;
  }
  if (bid < 1032) {
    const int i = bid - 8;
    const int ct = i & 31, b = i >> 5;
    const float* src = fmap + ((size_t)b * 1024 + ct * 32) * 576;
    const int tr = t >> 3, ti = t & 7;
    #pragma unroll
    for (int j = 0; j < 18; ++j) {
      int c4 = j * 8 + ti;
      *(f32x4*)&fmS[tr][c4 * 4] = *(const f32x4*)(src + (size_t)tr * 576 + c4 * 4);
    }
    __syncthreads();
    #pragma unroll
    for (int pass = 0; pass < 2; ++pass) {
      const int n = pass * 256 + t;
      const int pidx = b * 512 + n;
      float p0 = pts[(size_t)pidx * 2], p1 = pts[(size_t)pidx * 2 + 1];
      float gy = p0 * 23.f, gx = p1 * 23.f;
      float y0f = floorf(gy), x0f = floorf(gx);
      float wy = gy - y0f, wx = gx - x0f;
      int y0 = (int)y0f; y0 = y0 < 0 ? 0 : (y0 > 23 ? 23 : y0);
      int x0 = (int)x0f; x0 = x0 < 0 ? 0 : (x0 > 23 ? 23 : x0);
      int y1 = y0 + 1 > 23 ? 23 : y0 + 1;
      int x1 = x0 + 1 > 23 ? 23 : x0 + 1;
      float w00 = (1.f - wy) * (1.f - wx), w01 = (1.f - wy) * wx;
      float w10 = wy * (1.f - wx), w11 = wy * wx;
      const int i00 = y0 * 24 + x0, i01 = y0 * 24 + x1;
      const int i10 = y1 * 24 + x0, i11 = y1 * 24 + x1;
      size_t ro = (size_t)pidx * KP + ct * 32;
      #pragma unroll
      for (int cq = 0; cq < 8; ++cq) {
        u16x4 o4;
        #pragma unroll
        for (int cc = 0; cc < 4; ++cc) {
          int c = cq * 4 + cc;
          float v = w00 * fmS[c][i00] + w01 * fmS[c][i01] +
                    w10 * fmS[c][i10] + w11 * fmS[c][i11];
          o4[cc] = f2bf(v);
        }
        *(u16x4*)(X + ro + cq * 4) = o4;
      }
      if (ct == 31) {
        size_t rb = (size_t)pidx * KP;
        X[rb + 1024] = f2bf(p0);
        X[rb + 1025] = f2bf(p1);
        #pragma unroll
        for (int z = 0; z < 15; ++z) ((u32*)(X + rb + 1026))[z] = 0;
      }
    }
    return;
  }
  if (bid < 3408) {
    // wd_transpose: overlay tbuf[32][33] on fmS
    float (*tbuf)[33] = (float(*)[33])&fmS[0][0];
    const int i = bid - 1032;
    const int z = i / 1188;
    const int r = i % 1188;
    const int bx = r % 33, by = r / 33;
    const float* Wds = Wd + (size_t)z * 1026 * 1026;
    u16* WdTs = WdT + (size_t)z * NP0 * KP;
    int tx = t & 31, ty = t >> 5;
    int ot = bx * 32, dt = by * 32;
    #pragma unroll
    for (int j = 0; j < 4; ++j) {
      int o = ot + ty + 8 * j, d = dt + tx;
      tbuf[ty + 8 * j][tx] = (o < 1026 && d < 1026) ? Wds[(size_t)o * 1026 + d] : 0.f;
    }
    __syncthreads();
    #pragma unroll
    for (int j = 0; j < 4; ++j) {
      int d = dt + ty + 8 * j, o = ot + tx;
      if (o < KP) WdTs[(size_t)d * KP + o] = f2bf(tbuf[tx][ty + 8 * j]);
    }
    return;
  }
  {
    // waggcz: red[4] overlays fmS[0][0..3]
    float* red = &fmS[0][0];
    const int i = bid - 3408;
    const int stage = i >> 10, c = i & 1023;
    const float* row = Wagg + (size_t)stage * 1024 * 2052 + (size_t)c * 2052;
    const float* bd = bdiff + stage * 1026;
    u16* wa1 = Wa1 + (size_t)stage * 1024 * KP + (size_t)c * KP;
    u16* wa2 = Wa2 + (size_t)stage * 1024 * KP + (size_t)c * KP;
    float acc = 0.f;
    for (int d = t; d < KP; d += 256) {
      if (d < 1026) {
        float v1 = row[d];
        float v2 = row[1026 + d];
        wa1[d] = f2bf(v1);
        wa2[d] = f2bf(v2);
        acc += bd[d] * v1;
      } else {
        wa1[d] = 0;
        wa2[d] = 0;
      }
    }
    float s = wave_sum63(acc);
    if (lane == 63) red[wv] = s;
    __syncthreads();
    if (t == 0)
      czero[(size_t)stage * 1024 + c] = red[0] + red[1] + red[2] + red[3] + bagg[stage * 1024 + c];
  }
}

// Both Wcomb GEMMs (stage0 y in [1,8], stage1 y in [9,16]) + fps0 [32,64).
__global__ __launch_bounds__(256) void wcomb_dual_kernel(const u16* __restrict__ Wa1,
                                                         const u16* __restrict__ WdT,
                                                         u16* __restrict__ Wcomb,
                                                         const float* __restrict__ fpts,
                                                         int* __restrict__ ffi,
                                                         float* __restrict__ fnpts,
                                                         float* __restrict__ fdist,
                                                         int* __restrict__ ffar) {
  __shared__ __align__(16) u16 As[128 * 32];
  __shared__ __align__(16) u16 Bs[128 * 32];
  const int wv = threadIdx.x >> 6, lane = threadIdx.x & 63;
  if (blockIdx.y == 0) {
    if (blockIdx.x < 8)
      fps_core<8, 2>(fpts, ffi, fnpts, 512, 128, blockIdx.x * 4 + wv, lane, 32, 64,
                     fdist, ffar);
    return;
  }
  const int y = blockIdx.y - 1;
  const int stage = y >> 3;
  const int mt = y & 7;
  const u16* A = Wa1 + (size_t)stage * 1024 * KP;
  const u16* B = WdT + (size_t)stage * NP0 * KP;
  u16* C = Wcomb + (size_t)stage * 1024 * KP;
  gemm_tile_body<1, 0>(A, B, C, KP, KP, KP, mt * 128, blockIdx.x * 128,
                       nullptr, 0, 0, As, Bs);
}

// ---------------- Z1 fused: fps0 [64,128) + Z1 GEMM (bf16 out) --------------
// y==0: fps | y in [1,129): 128 m-tiles (XCD-swizzled).
__global__ __launch_bounds__(256) void z1_fused_kernel(const u16* __restrict__ A,
                                                       const u16* __restrict__ Bt,
                                                       u16* __restrict__ C,
                                                       const float* __restrict__ fpts,
                                                       int* __restrict__ ffi,
                                                       float* __restrict__ fnpts,
                                                       float* __restrict__ fdist,
                                                       int* __restrict__ ffar) {
  const int t = threadIdx.x;
  const int lane = t & 63, wv = t >> 6;
  if (blockIdx.y == 0) {
    if (blockIdx.x < 8)
      fps_core<8, 2>(fpts, ffi, fnpts, 512, 128, blockIdx.x * 4 + wv, lane, 64, 128,
                     fdist, ffar);
    return;
  }
  __shared__ __align__(16) u16 As[128 * 32];
  __shared__ __align__(16) u16 Bs[128 * 32];
  const int g = ((int)blockIdx.y - 1) * 8 + blockIdx.x;
  const int xcd = g & 7;
  const int r = g >> 3;
  const int mt = xcd * 16 + (r >> 3);  // MT=128, cpx=16
  const int nt = r & 7;
  gemm_tile_body<1, 0>(A, Bt, C, KP, 1024, 1024, mt * 128, nt * 128,
                       nullptr, 0, 0, As, Bs);
}

// ---------------- general MFMA GEMM dispatch (Z2 + knn0) --------------------
template <int BF16OUT, int SWZ, int KNN_PPL, int IND>
__global__ __launch_bounds__(256) void gemm_bt_kernel(const u16* __restrict__ A,
                                                      const u16* __restrict__ Bt,
                                                      void* __restrict__ Cout,
                                                      int K, int ldc, int nvalid,
                                                      const int* __restrict__ find,
                                                      int iNp, int iS,
                                                      const float* __restrict__ kq,
                                                      const float* __restrict__ kr,
                                                      int* __restrict__ kidx,
                                                      int kNp, int kS, int kYoff) {
  const int tid = threadIdx.x;
  const int lane = tid & 63;
  const int wv = tid >> 6;
  if (KNN_PPL > 0 && (int)blockIdx.y >= kYoff) {
    int kb = ((int)blockIdx.y - kYoff) * gridDim.x + blockIdx.x;
    knn_core<KNN_PPL ? KNN_PPL : 1>(kq, kr, kidx, kNp, kS, kb * 4 + wv, lane);
    return;
  }
  __shared__ __align__(16) u16 As[128 * 32];
  __shared__ __align__(16) u16 Bs[128 * 32];
  int mt, nt;
  if (SWZ) {
    const int g = (int)blockIdx.y * gridDim.x + blockIdx.x;
    const int MT = (KNN_PPL > 0 ? kYoff : (int)gridDim.y);
    const int cpx = MT >> 3;
    const int xcd = g & 7;
    const int r = g >> 3;
    mt = xcd * cpx + (r >> 3);
    nt = r & 7;
  } else {
    mt = (int)blockIdx.y;
    nt = blockIdx.x;
  }
  gemm_tile_body<BF16OUT, IND>(A, Bt, Cout, K, ldc, nvalid, mt * 128, nt * 128,
                               find, iNp, iS, As, Bs);
}

// ---------------- stage-1 fused: Z1'(bf16) + Z2'(indirect) + knn1 -----------
// y in [0,32): Z1' tiles (swz MT=32) | y in [32,40): Z2' (IND) | y in [40,72): knn1
__global__ __launch_bounds__(256) void stage1_fused_kernel(const u16* __restrict__ X1bf,
                                                           const u16* __restrict__ Wcomb1,
                                                           const u16* __restrict__ Wa21,
                                                           u16* __restrict__ Z1,
                                                           float* __restrict__ Z2g,
                                                           const int* __restrict__ fi1,
                                                           const float* __restrict__ npts1,
                                                           const float* __restrict__ npts0,
                                                           int* __restrict__ idx1) {
  __shared__ __align__(16) u16 As[128 * 32];
  __shared__ __align__(16) u16 Bs[128 * 32];
  const int lane = threadIdx.x & 63, wv = threadIdx.x >> 6;
  if (blockIdx.y < 32) {
    const int g = (int)blockIdx.y * 8 + blockIdx.x;
    const int xcd = g & 7;
    const int r = g >> 3;
    const int mt = xcd * 4 + (r >> 3);  // MT=32, cpx=4
    const int nt = r & 7;
    gemm_tile_body<1, 0>(X1bf, Wcomb1, Z1, KP, 1024, 1024, mt * 128, nt * 128,
                         nullptr, 0, 0, As, Bs);
    return;
  }
  if (blockIdx.y < 40) {
    const int mt = (int)blockIdx.y - 32;
    const int nt = blockIdx.x;
    gemm_tile_body<0, 1>(X1bf, Wa21, Z2g, KP, 1024, 1024, mt * 128, nt * 128,
                         fi1, 128, 32, As, Bs);
    return;
  }
  const int kb = ((int)blockIdx.y - 40) * 8 + blockIdx.x;
  knn_core<2>(npts1, npts0, idx1, 128, 32, kb * 4 + wv, lane);
}

// ---------------- fused gather + relu + LN + mean_k -------------------------
// Wave-per-q, DPP add-scan LN, XCD-bijective swizzle. Z1 is bf16 (exact
// widening on read); Z2/czero fp32. FPS_PPL>0: first 8 blocks run fps_core.
template <int MODE, int FPS_PPL, int FPS_HS>
__global__ __launch_bounds__(256) void h_epilogue_kernel(const u16* __restrict__ Z1,
                                                         const float* __restrict__ Z2g,
                                                         const float* __restrict__ czero,
                                                         const int* __restrict__ idxK,
                                                         const int* __restrict__ fi,
                                                         const float* __restrict__ g,
                                                         const float* __restrict__ bb,
                                                         const float* __restrict__ npts,
                                                         void* __restrict__ outp,
                                                         int Np, int S, int cpx,
                                                         const float* __restrict__ fpts,
                                                         int* __restrict__ ffi,
                                                         float* __restrict__ fnpts,
                                                         int fNp, int fS) {
  const int t = threadIdx.x;
  const int lane = t & 63, wv = t >> 6;
  if (FPS_PPL > 0 && blockIdx.x < 8) {
    fps_core<FPS_PPL ? FPS_PPL : 1, FPS_HS>(fpts, ffi, fnpts, fNp, fS,
                                            blockIdx.x * 4 + wv, lane, 0, fS,
                                            nullptr, nullptr);
    return;
  }
  const int bid = blockIdx.x - (FPS_PPL > 0 ? 8 : 0);
  const int sw = (bid & 7) * cpx + (bid >> 3);  // XCD-contiguous q ranges
  const int q = sw * 4 + wv;
  const int b = q / S;
  const int fiv = fi[q];
  const float* z2 = Z2g + (size_t)q * 1024;
  const u16* zf = Z1 + ((size_t)b * Np + fiv) * 1024;
  const int ch = lane * 4;  // + j*256

  f32x4 base[4], gv[4], bv[4], acc[4];
  #pragma unroll
  for (int j = 0; j < 4; ++j) {
    f32x4 a = *(const f32x4*)(z2 + j * 256 + ch);
    f32x4 c = *(const f32x4*)(czero + j * 256 + ch);
    u16x4 f = *(const u16x4*)(zf + j * 256 + ch);
    #pragma unroll
    for (int c2 = 0; c2 < 4; ++c2) base[j][c2] = a[c2] + c[c2] - bf2f(f[c2]);
    gv[j] = *(const f32x4*)(g + j * 256 + ch);
    bv[j] = *(const f32x4*)(bb + j * 256 + ch);
    #pragma unroll
    for (int c2 = 0; c2 < 4; ++c2) acc[j][c2] = 0.f;
  }
  int nk = 0;
  if (lane < 24) nk = idxK[(size_t)q * 24 + lane];

  for (int k = 0; k < 24; ++k) {
    const int n = __builtin_amdgcn_readlane(nk, k);
    const u16* zr = Z1 + ((size_t)b * Np + n) * 1024;
    f32x4 v[4];
    float s1 = 0.f, s2 = 0.f;
    #pragma unroll
    for (int j = 0; j < 4; ++j) {
      u16x4 r = *(const u16x4*)(zr + j * 256 + ch);
      #pragma unroll
      for (int c2 = 0; c2 < 4; ++c2) {
        float x = fmaxf(bf2f(r[c2]) + base[j][c2], 0.f);
        v[j][c2] = x;
        s1 += x;
        s2 += x * x;
      }
    }
    s1 = wave_sum63(s1);
    s2 = wave_sum63(s2);
    const float S1 = rl_f(s1, 63);
    const float S2 = rl_f(s2, 63);
    const float m = S1 * (1.f / 1024.f);
    const float var = S2 * (1.f / 1024.f) - m * m;
    const float rs = rsqrtf(var + 1e-5f);
    #pragma unroll
    for (int j = 0; j < 4; ++j)
      #pragma unroll
      for (int c2 = 0; c2 < 4; ++c2)
        acc[j][c2] += (v[j][c2] - m) * rs * gv[j][c2] + bv[j][c2];
  }

  u16x4 o4[4];
  #pragma unroll
  for (int j = 0; j < 4; ++j)
    #pragma unroll
    for (int c2 = 0; c2 < 4; ++c2) o4[j][c2] = f2bf(acc[j][c2] * (1.f / 24.f));

  if (MODE == 0) {
    u16* X = (u16*)outp;
    size_t ro = (size_t)q * KP;
    #pragma unroll
    for (int j = 0; j < 4; ++j) *(u16x4*)(X + ro + j * 256 + ch) = o4[j];
    if (lane == 0) {
      X[ro + 1024] = f2bf(npts[(size_t)q * 2]);
      X[ro + 1025] = f2bf(npts[(size_t)q * 2 + 1]);
    }
    if (lane < 15) ((u32*)(X + ro + 1026))[lane] = 0;
  } else {
    u16* X = (u16*)outp + (size_t)q * 1024;
    #pragma unroll
    for (int j = 0; j < 4; ++j) *(u16x4*)(X + j * 256 + ch) = o4[j];
  }
}

// ---------------- MLP MFMA GEMM (fp32 A): P[blk] = W_tile(->bf16) @ Fb^T ----
template <int KSBITS, int NST>
__global__ __launch_bounds__(256, 4) void mlp_mfma_kernel(const float* __restrict__ W,
                                                          const u16* __restrict__ Fb,
                                                          float* __restrict__ P, int K) {
  __shared__ __align__(16) float Asf[128 * 32];
  __shared__ __align__(16) u16 Fsb[32 * 40];
  const int tid = threadIdx.x, lane = tid & 63, wv = tid >> 6;
  const int ot = blockIdx.x >> KSBITS;
  const int ks = blockIdx.x & ((1 << KSBITS) - 1);
  const int m0 = ot * 128;
  const int k0b = ks * (NST * 32);
  const int arow = lane >> 3;
  const int agrp = lane & 7;
  const int rf = lane & 15, quad = lane >> 4;

  f32x4 acc[2][2];
  #pragma unroll
  for (int i = 0; i < 2; ++i)
    #pragma unroll
    for (int j = 0; j < 2; ++j)
      #pragma unroll
      for (int c = 0; c < 4; ++c) acc[i][j][c] = 0.f;

  for (int st = 0; st < NST; ++st) {
    const int k0 = k0b + st * 32;
    #pragma unroll
    for (int i = 0; i < 4; ++i) {
      const int row = wv * 32 + i * 8 + arow;
      const int g = agrp ^ (row & 7);
      const float* ga = W + (size_t)(m0 + row) * K + k0 + g * 4;
      __builtin_amdgcn_global_load_lds((gvp)ga, (svp)(Asf + (wv * 32 + i * 8) * 32), 16, 0, 0);
    }
    if (tid < 128) {
      const int fr = tid >> 2, fc = (tid & 3) * 8;
      u32x4 tmp = *(const u32x4*)(Fb + (size_t)fr * K + k0 + fc);
      *(u32x4*)(Fsb + fr * 40 + fc) = tmp;
    }
    __syncthreads();
    bf16x8 bfr[2];
    #pragma unroll
    for (int ni = 0; ni < 2; ++ni)
      bfr[ni] = *(const bf16x8*)(Fsb + (ni * 16 + rf) * 40 + quad * 8);
    #pragma unroll
    for (int mi = 0; mi < 2; ++mi) {
      const float* ap = Asf + (size_t)(wv * 32 + mi * 16 + rf) * 32;
      f32x4 a0 = *(const f32x4*)(ap + (((quad * 2) ^ (rf & 7)) * 4));
      f32x4 a1 = *(const f32x4*)(ap + (((quad * 2 + 1) ^ (rf & 7)) * 4));
      union { bf16x8 v; u16 h[8]; } af;
      #pragma unroll
      for (int c = 0; c < 4; ++c) { af.h[c] = f2bf(a0[c]); af.h[4 + c] = f2bf(a1[c]); }
      #pragma unroll
      for (int ni = 0; ni < 2; ++ni)
        acc[mi][ni] = __builtin_amdgcn_mfma_f32_16x16x32_bf16(af.v, bfr[ni], acc[mi][ni], 0, 0, 0);
    }
    __syncthreads();
  }

  float* Pb = P + (size_t)blockIdx.x * 4096;
  const int rq = (lane >> 4) * 4, cf = lane & 15;
  #pragma unroll
  for (int mi = 0; mi < 2; ++mi)
    #pragma unroll
    for (int ni = 0; ni < 2; ++ni)
      #pragma unroll
      for (int r = 0; r < 4; ++r)
        Pb[(wv * 32 + mi * 16 + rq + r) * 32 + ni * 16 + cf] = acc[mi][ni][r];
}

// ---------------- K-split partial reductions (bias fused) -------------------
__global__ __launch_bounds__(256) void reduce_flat_kernel(const float* __restrict__ P,
                                                          const float* __restrict__ bias,
                                                          u16* __restrict__ x1bf) {
  int idx = blockIdx.x * 256 + threadIdx.x;  // 32768
  int o = idx >> 5, b = idx & 31;
  float s = bias[o];
  const float* p = P + ((size_t)(o >> 7) * 64) * 4096 + (o & 127) * 32 + b;
  #pragma unroll 8
  for (int ks = 0; ks < 64; ++ks) s += p[(size_t)ks * 4096];
  x1bf[(size_t)b * 1024 + o] = f2bf(s);
}

__global__ __launch_bounds__(256) void reduce_dim_kernel(const float* __restrict__ P,
                                                         const float* __restrict__ bias,
                                                         float* __restrict__ out) {
  int idx = blockIdx.x * 256 + threadIdx.x;  // 131072
  int o = idx >> 5, b = idx & 31;
  float s = bias[o];
  const float* p = P + ((size_t)(o >> 7) * 8) * 4096 + (o & 127) * 32 + b;
  #pragma unroll
  for (int ks = 0; ks < 8; ++ks) s += p[(size_t)ks * 4096];
  out[(size_t)b * 4096 + o] = s;
}

// ---------------------------------------------------------------------------
extern "C" void kernel_launch(void* const* d_in, const int* in_sizes, int n_in,
                              void* d_out, int out_size, void* d_ws, size_t ws_size,
                              hipStream_t stream) {
  const float* fmap  = (const float*)d_in[0];
  const float* pts   = (const float*)d_in[1];
  const float* Wdiff = (const float*)d_in[2];
  const float* bdiff = (const float*)d_in[3];
  const float* Wagg  = (const float*)d_in[4];
  const float* bagg  = (const float*)d_in[5];
  const float* lng   = (const float*)d_in[6];
  const float* lnb   = (const float*)d_in[7];
  const float* Wflat = (const float*)d_in[8];
  const float* bflat = (const float*)d_in[9];
  const float* Wdim  = (const float*)d_in[10];
  const float* bdim  = (const float*)d_in[11];
  float* out = (float*)d_out;

  char* w = (char*)d_ws;
  size_t off = 0;
  auto alloc = [&](size_t n) { char* p = w + off; off += (n + 255) & ~(size_t)255; return p; };

  u16* Z1    = (u16*)alloc(16384ull * 1024 * 2);      // 33.5 MB bf16
  float* Z2g   = (float*)alloc(4096ull * 1024 * 4);   // 16.8 MB
  u16* Xbf0  = (u16*)alloc(16384ull * KP * 2);
  u16* X1bf  = (u16*)alloc(4096ull * KP * 2);
  u16* WdT   = (u16*)alloc(2ull * NP0 * KP * 2);      // both stages
  u16* Wa1   = (u16*)alloc(2ull * 1024 * KP * 2);
  u16* Wa2   = (u16*)alloc(2ull * 1024 * KP * 2);
  u16* Wcomb = (u16*)alloc(2ull * 1024 * KP * 2);
  float* czero = (float*)alloc(2 * 1024 * 4);
  int* fi0   = (int*)alloc(32 * 128 * 4);
  int* fi1   = (int*)alloc(32 * 32 * 4);
  int* idx0  = (int*)alloc(32 * 128 * 24 * 4);
  int* idx1  = (int*)alloc(32 * 32 * 24 * 4);
  float* npts0 = (float*)alloc(32 * 128 * 2 * 4);
  float* npts1 = (float*)alloc(32 * 32 * 2 * 4);
  u16* fea2bf = (u16*)alloc(32ull * 32768 * 2);       // 2 MB bf16
  u16* x1bf   = (u16*)alloc(32ull * 1024 * 2);        // 64 KB bf16
  float* Pf   = (float*)alloc(512ull * 4096 * 4);     // 8 MB partials (flat)
  float* Pd   = (float*)alloc(256ull * 4096 * 4);     // 4 MB partials (dim)
  float* fdist = (float*)alloc(32ull * 512 * 4);      // fps0 dist state
  int* ffar    = (int*)alloc(32 * 4);                 // fps0 far state

  // D1: bilinear + BOTH stages' weight prep + fps0 [0,32)
  input_prep_kernel<<<5456, 256, 0, stream>>>(fmap, pts, Xbf0,
                                              Wdiff, WdT, Wagg, bdiff, bagg,
                                              Wa1, Wa2, czero,
                                              fi0, npts0, fdist, ffar);
  // D2: both Wcomb GEMMs + fps0 [32,64)
  wcomb_dual_kernel<<<dim3(9, 17), 256, 0, stream>>>(Wa1, WdT, Wcomb, pts, fi0, npts0,
                                                     fdist, ffar);
  // D3: Z1 (stage0, bf16 out) + fps0 [64,128)
  z1_fused_kernel<<<dim3(8, 129), 256, 0, stream>>>(Xbf0, Wcomb, Z1,
                                                    pts, fi0, npts0, fdist, ffar);
  // D4: Z2 (A rows via fi0) + knn0
  gemm_bt_kernel<0, 1, 8, 1><<<dim3(8, 160), 256, 0, stream>>>(
      Xbf0, Wa2, Z2g, KP, 1024, 1024,
      fi0, 512, 128,
      npts0, pts, idx0, 512, 128, 32);
  // D5: h_epilogue0 + fps1 full [0,32)
  h_epilogue_kernel<0, 2, 1><<<1032, 256, 0, stream>>>(
      Z1, Z2g, czero, idx0, fi0, lng, lnb, npts0, X1bf, 512, 128, 128,
      npts0, fi1, npts1, 128, 32);
  // D6: stage-1 fused (Z1'(bf16) + Z2' + knn1)
  stage1_fused_kernel<<<dim3(8, 72), 256, 0, stream>>>(
      X1bf, Wcomb + 1024ull * KP, Wa2 + 1024ull * KP, Z1, Z2g, fi1,
      npts1, npts0, idx1);
  // D7: h_epilogue1
  h_epilogue_kernel<1, 0, 1><<<256, 256, 0, stream>>>(
      Z1, Z2g, czero + 1024, idx1, fi1, lng + 1024, lnb + 1024, npts1, fea2bf,
      128, 32, 32, nullptr, nullptr, nullptr, 0, 0);

  // D8-11: final MLP (MFMA, K-split partials + reduce)
  mlp_mfma_kernel<6, 16><<<512, 256, 0, stream>>>(Wflat, fea2bf, Pf, 32768);
  reduce_flat_kernel<<<128, 256, 0, stream>>>(Pf, bflat, x1bf);
  mlp_mfma_kernel<3, 4><<<256, 256, 0, stream>>>(Wdim, x1bf, Pd, 1024);
  reduce_dim_kernel<<<512, 256, 0, stream>>>(Pd, bdim, out);
}

// Round 13
// 511.277 us; speedup vs baseline: 1.0196x; 1.0196x over previous
//
#include <hip/hip_runtime.h>

// ---------------------------------------------------------------------------
// GeoRegionSampler: restructured pipeline
//   X = [bilinear_fea | pts] (bf16, padded 1026->1056)
//   Wcomb = Wa1 @ Wd ; Z1 = X @ Wcomb^T (bf16 out); Z2 = X[fi] @ Wa2^T (fp32)
//   h = relu(Z1[idx]-Z1[fi]+Z2+czero) -> LN -> mean_k (wave-per-q, DPP)
//   final MLP: MFMA GEMMs + K-split reduce.
// R17 (this round): revert R16's bilinear+prep merge.
//   R16 post-mortem: static LDS allocation is per-kernel, not per-path --
//   bilinear's 74KB fmS capped the merged dispatch at 2 blocks/CU, so the
//   prep streaming paths ran latency-bound at 1.34TB/s (17% HBM) instead
//   of ~5TB/s: one 78us dispatch replaced a 22+18us pair. Same genus as
//   R11's fusion failure (co-located workloads couple resource budgets:
//   VGPR then, LDS now). Reverted to the R15 structure that measured
//   512.58us (session best):
//   - D1 bilinear_fused (74KB LDS, own path only) + fps0 [0,32)
//   - D2 prep_merged (small LDS, high occupancy) + fps0 [32,56)
//   - D3 wcomb_dual + fps0 [56,78) | D4 z1_fused + fps0 [78,128)
//   Carried: noinline fps/knn cores, bf16 Z1, fi-indirect Z2, wave-per-q
//   DPP epilogue, XCD-bijective remap, fp32 mlp_mfma.
// ---------------------------------------------------------------------------

typedef float f32x4 __attribute__((ext_vector_type(4)));
typedef short bf16x8 __attribute__((ext_vector_type(8)));
typedef unsigned short u16;
typedef u16 u16x4 __attribute__((ext_vector_type(4)));
typedef unsigned int u32;
typedef u32 u32x4 __attribute__((ext_vector_type(4)));
typedef unsigned long long u64;

typedef const void __attribute__((address_space(1)))* gvp;
typedef void __attribute__((address_space(3)))* svp;

__device__ __forceinline__ u16 f2bf(float f) {
  union { float f; u32 u; } x; x.f = f;
  u32 r = x.u + 0x7fffu + ((x.u >> 16) & 1u);
  return (u16)(r >> 16);
}

__device__ __forceinline__ float bf2f(u16 h) {
  union { u32 u; float f; } x; x.u = ((u32)h) << 16;
  return x.f;
}

#define KP 1056   // padded Dp (1026 -> 33*32)
#define NP0 1152  // padded N for weight-combine GEMM (9*128)

// ---- DPP cross-lane helpers (VALU pipe) -----------------------------------
__device__ __forceinline__ float rl_f(float v, int lane) {
  return __int_as_float(__builtin_amdgcn_readlane(__float_as_int(v), lane));
}

template <int CTRL>
__device__ __forceinline__ float dpp_fmax(float v) {
  float o = __int_as_float(__builtin_amdgcn_update_dpp(
      (int)0xff800000 /* -inf */, __float_as_int(v), CTRL, 0xf, 0xf, false));
  return fmaxf(v, o);
}

template <int CTRL>
__device__ __forceinline__ float dpp_fmin(float v) {
  float o = __int_as_float(__builtin_amdgcn_update_dpp(
      0x7f800000 /* +inf */, __float_as_int(v), CTRL, 0xf, 0xf, false));
  return fminf(v, o);
}

template <int CTRL>
__device__ __forceinline__ float dpp_add(float v) {
  float o = __int_as_float(__builtin_amdgcn_update_dpp(
      0, __float_as_int(v), CTRL, 0xf, 0xf, false));
  return v + o;
}

__device__ __forceinline__ float wave_fmax63(float v) {
  v = dpp_fmax<0x111>(v);
  v = dpp_fmax<0x112>(v);
  v = dpp_fmax<0x114>(v);
  v = dpp_fmax<0x118>(v);
  v = dpp_fmax<0x142>(v);
  v = dpp_fmax<0x143>(v);
  return rl_f(v, 63);
}

__device__ __forceinline__ float wave_fmin63(float v) {
  v = dpp_fmin<0x111>(v);
  v = dpp_fmin<0x112>(v);
  v = dpp_fmin<0x114>(v);
  v = dpp_fmin<0x118>(v);
  v = dpp_fmin<0x142>(v);
  v = dpp_fmin<0x143>(v);
  return rl_f(v, 63);
}

__device__ __forceinline__ float wave_sum63(float v) {
  v = dpp_add<0x111>(v);
  v = dpp_add<0x112>(v);
  v = dpp_add<0x114>(v);
  v = dpp_add<0x118>(v);
  v = dpp_add<0x142>(v);
  v = dpp_add<0x143>(v);
  return v;
}

// ---------------- FPS core: one wave per batch, bit-exact -------------------
// Resumable [s0,s1); dist/far state spilled as raw fp32 bits (exact).
// Emits fi AND npts (coords copied bit-exact from pts) for its own range.
// noinline: keeps this path's regalloc out of the host GEMM kernel's body.
template <int PPL, int HS>
__device__ __attribute__((noinline)) void fps_core(
    const float* __restrict__ pts, int* __restrict__ fi,
    float* __restrict__ npts,
    int Np, int S, int b, int lane, int s0, int s1,
    float* __restrict__ dsave, int* __restrict__ fsave) {
  #pragma clang fp contract(off)
  float px[PPL], py[PPL], dist[PPL];
  #pragma unroll
  for (int j = 0; j < PPL; ++j) {
    int n = j * 64 + lane;
    px[j] = pts[((size_t)b * Np + n) * 2];
    py[j] = pts[((size_t)b * Np + n) * 2 + 1];
  }
  int far; float cx, cy;
  if (s0 == 0) {
    #pragma unroll
    for (int j = 0; j < PPL; ++j) dist[j] = 1e10f;
    far = 0;
    cx = rl_f(px[0], 0);
    cy = rl_f(py[0], 0);
  } else {
    #pragma unroll
    for (int j = 0; j < PPL; ++j) dist[j] = dsave[(size_t)b * Np + j * 64 + lane];
    far = fsave[b];
    cx = pts[((size_t)b * Np + far) * 2];
    cy = pts[((size_t)b * Np + far) * 2 + 1];
  }
  int hist[HS];
  #pragma unroll
  for (int h = 0; h < HS; ++h) hist[h] = 0;
  for (int s = s0; s < s1; ++s) {
    #pragma unroll
    for (int h = 0; h < HS; ++h)
      if ((s >> 6) == h && (s & 63) == lane) hist[h] = far;
    float bv = -1.f; int bi = 0; float bx = 0.f, by = 0.f;
    #pragma unroll
    for (int j = 0; j < PPL; ++j) {
      float dx = px[j] - cx, dy = py[j] - cy;
      float d = dx * dx + dy * dy;
      float nd = fminf(dist[j], d);
      dist[j] = nd;
      if (nd > bv) { bv = nd; bi = j * 64 + lane; bx = px[j]; by = py[j]; }
    }
    float smax = wave_fmax63(bv);
    u64 mask = __ballot(bv == smax);
    int L = __builtin_ctzll(mask);
    int fidx = __builtin_amdgcn_readlane(bi, L);
    float fx = rl_f(bx, L), fy = rl_f(by, L);
    u64 rest = mask & (mask - 1);
    if (__builtin_expect(rest != 0, 0)) {
      // rare: multiple lanes hold the max value -> exact min-index tiebreak
      while (rest) {
        int L2 = __builtin_ctzll(rest);
        int c = __builtin_amdgcn_readlane(bi, L2);
        if (c < fidx) {
          fidx = c; fx = rl_f(bx, L2); fy = rl_f(by, L2);
        }
        rest &= rest - 1;
      }
    }
    far = fidx; cx = fx; cy = fy;
  }
  if (s1 < S) {
    #pragma unroll
    for (int j = 0; j < PPL; ++j) dsave[(size_t)b * Np + j * 64 + lane] = dist[j];
    if (lane == 0) fsave[b] = far;
  }
  #pragma unroll
  for (int h = 0; h < HS; ++h) {
    int s = h * 64 + lane;
    if (s >= s0 && s < s1) {
      int hv = hist[h];
      fi[b * S + s] = hv;
      npts[(size_t)(b * S + s) * 2]     = pts[((size_t)b * Np + hv) * 2];
      npts[(size_t)(b * S + s) * 2 + 1] = pts[((size_t)b * Np + hv) * 2 + 1];
    }
  }
}

// ---------------- kNN core: one wave per q, bit-exact -----------------------
template <int PPL>
__device__ __attribute__((noinline)) void knn_core(
    const float* __restrict__ qpts,
    const float* __restrict__ rpts,
    int* __restrict__ idxK, int Np, int S, int q, int lane) {
  #pragma clang fp contract(off)
  int b = q / S;
  float ax = qpts[(size_t)q * 2], ay = qpts[(size_t)q * 2 + 1];
  float a2 = ax * ax + ay * ay;
  float d2[PPL];
  #pragma unroll
  for (int j = 0; j < PPL; ++j) {
    int n = j * 64 + lane;
    float bx = rpts[((size_t)b * Np + n) * 2];
    float by = rpts[((size_t)b * Np + n) * 2 + 1];
    float b2 = bx * bx + by * by;
    float dot = ax * bx + ay * by;
    float t = a2 + b2;
    float m2 = 2.f * dot;
    d2[j] = t - m2;
  }
  int kreg = 0;
  for (int k = 0; k < 24; ++k) {
    float bv = 3.4e38f; int bi = 1 << 30;
    #pragma unroll
    for (int j = 0; j < PPL; ++j)
      if (d2[j] < bv) { bv = d2[j]; bi = j * 64 + lane; }
    float smin = wave_fmin63(bv);
    u64 mask = __ballot(bv == smin);
    int L = __builtin_ctzll(mask);
    int bs = __builtin_amdgcn_readlane(bi, L);
    u64 rest = mask & (mask - 1);
    if (__builtin_expect(rest != 0, 0)) {
      while (rest) {
        int L2 = __builtin_ctzll(rest);
        int c = __builtin_amdgcn_readlane(bi, L2);
        if (c < bs) bs = c;
        rest &= rest - 1;
      }
    }
    if (lane == k) kreg = bs;
    #pragma unroll
    for (int j = 0; j < PPL; ++j)
      if (j * 64 + lane == bs) d2[j] = 3.4e38f;
  }
  if (lane < 24) idxK[(size_t)q * 24 + lane] = kreg;
}

// ---------------- GEMM tile body (shared by all MFMA GEMMs) -----------------
// IND: A rows indexed via find[] (q -> b*iNp + find[q]); C rows stay direct.
// LDS: both-sides XOR swizzle on 16B slots (linear dest for global_load_lds).
template <int BF16OUT, int IND>
__device__ __forceinline__ void gemm_tile_body(const u16* __restrict__ A,
                                               const u16* __restrict__ Bt,
                                               void* __restrict__ Cout,
                                               int K, int ldc, int nvalid,
                                               int m0, int n0,
                                               const int* __restrict__ find,
                                               int iNp, int iS,
                                               u16* __restrict__ As,
                                               u16* __restrict__ Bs) {
  const int tid = threadIdx.x;
  const int lane = tid & 63;
  const int wv = tid >> 6;
  const int wm = (wv >> 1) * 64;
  const int wn = (wv & 1) * 64;

  f32x4 acc[4][4];
  #pragma unroll
  for (int i = 0; i < 4; ++i)
    #pragma unroll
    for (int j = 0; j < 4; ++j)
      #pragma unroll
      for (int c = 0; c < 4; ++c) acc[i][j][c] = 0.f;

  const int ch0 = wv * 2;
  const int rin = lane >> 2;
  const int slot = lane & 3;
  const int cin = (slot ^ (rin & 3) ^ ((rin >> 2) & 3)) * 8;  // pre-swizzled src col

  size_t aro[2];
  #pragma unroll
  for (int i = 0; i < 2; ++i) {
    const int row = (ch0 + i) * 16 + rin;
    if (IND) {
      const int q = m0 + row;
      aro[i] = (size_t)(q / iS) * iNp + find[q];
    } else {
      aro[i] = (size_t)(m0 + row);
    }
  }

  for (int k0 = 0; k0 < K; k0 += 32) {
    #pragma unroll
    for (int i = 0; i < 2; ++i) {
      const int ch = ch0 + i;
      const int row = ch * 16 + rin;
      const u16* ga = A + aro[i] * K + (k0 + cin);
      const u16* gb = Bt + (size_t)(n0 + row) * K + (k0 + cin);
      __builtin_amdgcn_global_load_lds((gvp)ga, (svp)(As + ch * 512), 16, 0, 0);
      __builtin_amdgcn_global_load_lds((gvp)gb, (svp)(Bs + ch * 512), 16, 0, 0);
    }
    __syncthreads();
    const int rf = lane & 15;
    const int quad = lane >> 4;
    const int qs = (quad ^ (rf & 3) ^ ((rf >> 2) & 3)) * 8;  // swizzled read slot
    bf16x8 af[4], bfv[4];
    #pragma unroll
    for (int mi = 0; mi < 4; ++mi)
      af[mi] = *(const bf16x8*)(As + (wm + mi * 16 + rf) * 32 + qs);
    #pragma unroll
    for (int ni = 0; ni < 4; ++ni)
      bfv[ni] = *(const bf16x8*)(Bs + (wn + ni * 16 + rf) * 32 + qs);
    #pragma unroll
    for (int mi = 0; mi < 4; ++mi)
      #pragma unroll
      for (int ni = 0; ni < 4; ++ni)
        acc[mi][ni] = __builtin_amdgcn_mfma_f32_16x16x32_bf16(af[mi], bfv[ni], acc[mi][ni], 0, 0, 0);
    __syncthreads();
  }

  const int rq = (lane >> 4) * 4;
  const int cf = lane & 15;
  #pragma unroll
  for (int mi = 0; mi < 4; ++mi) {
    #pragma unroll
    for (int ni = 0; ni < 4; ++ni) {
      const int col = n0 + wn + ni * 16 + cf;
      #pragma unroll
      for (int r = 0; r < 4; ++r) {
        const int row = m0 + wm + mi * 16 + rq + r;
        const float v = acc[mi][ni][r];
        if (BF16OUT) {
          if (col < nvalid) ((u16*)Cout)[(size_t)row * ldc + col] = f2bf(v);
        } else {
          ((float*)Cout)[(size_t)row * ldc + col] = v;
        }
      }
    }
  }
}

// ------- fused bilinear + fps0 segment [0,32) (y==0 row) -------------------
__global__ __launch_bounds__(256, 2) void bilinear_fused_kernel(const float* __restrict__ fmap,
                                                                const float* __restrict__ pts,
                                                                u16* __restrict__ X,
                                                                int* __restrict__ fi0,
                                                                float* __restrict__ npts0,
                                                                float* __restrict__ fdist,
                                                                int* __restrict__ ffar) {
  if (blockIdx.y == 0) {
    if (blockIdx.x < 8)
      fps_core<8, 2>(pts, fi0, npts0, 512, 128, blockIdx.x * 4 + (threadIdx.x >> 6),
                     threadIdx.x & 63, 0, 32, fdist, ffar);
    return;
  }
  __shared__ float fmS[32][580];
  const int ct = blockIdx.x, b = blockIdx.y - 1;
  const int t = threadIdx.x;
  const float* src = fmap + ((size_t)b * 1024 + ct * 32) * 576;
  const int tr = t >> 3, ti = t & 7;
  #pragma unroll
  for (int j = 0; j < 18; ++j) {
    int c4 = j * 8 + ti;
    *(f32x4*)&fmS[tr][c4 * 4] = *(const f32x4*)(src + (size_t)tr * 576 + c4 * 4);
  }
  __syncthreads();
  #pragma unroll
  for (int pass = 0; pass < 2; ++pass) {
    const int n = pass * 256 + t;
    const int pidx = b * 512 + n;
    float p0 = pts[(size_t)pidx * 2], p1 = pts[(size_t)pidx * 2 + 1];
    float gy = p0 * 23.f, gx = p1 * 23.f;
    float y0f = floorf(gy), x0f = floorf(gx);
    float wy = gy - y0f, wx = gx - x0f;
    int y0 = (int)y0f; y0 = y0 < 0 ? 0 : (y0 > 23 ? 23 : y0);
    int x0 = (int)x0f; x0 = x0 < 0 ? 0 : (x0 > 23 ? 23 : x0);
    int y1 = y0 + 1 > 23 ? 23 : y0 + 1;
    int x1 = x0 + 1 > 23 ? 23 : x0 + 1;
    float w00 = (1.f - wy) * (1.f - wx), w01 = (1.f - wy) * wx;
    float w10 = wy * (1.f - wx), w11 = wy * wx;
    const int i00 = y0 * 24 + x0, i01 = y0 * 24 + x1;
    const int i10 = y1 * 24 + x0, i11 = y1 * 24 + x1;
    size_t ro = (size_t)pidx * KP + ct * 32;
    #pragma unroll
    for (int cq = 0; cq < 8; ++cq) {
      u16x4 o4;
      #pragma unroll
      for (int cc = 0; cc < 4; ++cc) {
        int c = cq * 4 + cc;
        float v = w00 * fmS[c][i00] + w01 * fmS[c][i01] +
                  w10 * fmS[c][i10] + w11 * fmS[c][i11];
        o4[cc] = f2bf(v);
      }
      *(u16x4*)(X + ro + cq * 4) = o4;
    }
    if (ct == 31) {
      size_t rb = (size_t)pidx * KP;
      X[rb + 1024] = f2bf(p0);
      X[rb + 1025] = f2bf(p1);
      #pragma unroll
      for (int z = 0; z < 15; ++z) ((u32*)(X + rb + 1026))[z] = 0;
    }
  }
}

// ---------------- merged prep: wd_transpose + waggcz + fps0 [32,56) ---------
// blocks: [0,8) fps | [8, 8+2376) wdT (33 x 36 x 2) | [2384, 4432) waggcz
__global__ __launch_bounds__(256) void prep_merged_kernel(const float* __restrict__ Wd,
                                                          u16* __restrict__ WdT,
                                                          const float* __restrict__ Wagg,
                                                          const float* __restrict__ bdiff,
                                                          const float* __restrict__ bagg,
                                                          u16* __restrict__ Wa1,
                                                          u16* __restrict__ Wa2,
                                                          float* __restrict__ czero,
                                                          const float* __restrict__ fpts,
                                                          int* __restrict__ ffi,
                                                          float* __restrict__ fnpts,
                                                          float* __restrict__ fdist,
                                                          int* __restrict__ ffar) {
  __shared__ float tbuf[32][33];
  __shared__ float red[4];
  const int bid = blockIdx.x;
  const int t = threadIdx.x;
  const int lane = t & 63, wv = t >> 6;
  if (bid < 8) {
    fps_core<8, 2>(fpts, ffi, fnpts, 512, 128, bid * 4 + wv, lane, 32, 56, fdist, ffar);
    return;
  }
  if (bid < 8 + 2376) {
    const int i = bid - 8;
    const int z = i / 1188;
    const int r = i % 1188;
    const int bx = r % 33, by = r / 33;
    const float* Wds = Wd + (size_t)z * 1026 * 1026;
    u16* WdTs = WdT + (size_t)z * NP0 * KP;
    int tx = t & 31, ty = t >> 5;
    int ot = bx * 32, dt = by * 32;
    #pragma unroll
    for (int j = 0; j < 4; ++j) {
      int o = ot + ty + 8 * j, d = dt + tx;
      tbuf[ty + 8 * j][tx] = (o < 1026 && d < 1026) ? Wds[(size_t)o * 1026 + d] : 0.f;
    }
    __syncthreads();
    #pragma unroll
    for (int j = 0; j < 4; ++j) {
      int d = dt + ty + 8 * j, o = ot + tx;
      if (o < KP) WdTs[(size_t)d * KP + o] = f2bf(tbuf[tx][ty + 8 * j]);
    }
    return;
  }
  const int i = bid - (8 + 2376);
  const int stage = i >> 10, c = i & 1023;
  const float* row = Wagg + (size_t)stage * 1024 * 2052 + (size_t)c * 2052;
  const float* bd = bdiff + stage * 1026;
  u16* wa1 = Wa1 + (size_t)stage * 1024 * KP + (size_t)c * KP;
  u16* wa2 = Wa2 + (size_t)stage * 1024 * KP + (size_t)c * KP;
  float acc = 0.f;
  for (int d = t; d < KP; d += 256) {
    if (d < 1026) {
      float v1 = row[d];
      float v2 = row[1026 + d];
      wa1[d] = f2bf(v1);
      wa2[d] = f2bf(v2);
      acc += bd[d] * v1;
    } else {
      wa1[d] = 0;
      wa2[d] = 0;
    }
  }
  float s = wave_sum63(acc);
  if (lane == 63) red[wv] = s;
  __syncthreads();
  if (t == 0)
    czero[(size_t)stage * 1024 + c] = red[0] + red[1] + red[2] + red[3] + bagg[stage * 1024 + c];
}

// Both Wcomb GEMMs (stage0 y in [1,8], stage1 y in [9,16]) + fps0 [56,78).
__global__ __launch_bounds__(256) void wcomb_dual_kernel(const u16* __restrict__ Wa1,
                                                         const u16* __restrict__ WdT,
                                                         u16* __restrict__ Wcomb,
                                                         const float* __restrict__ fpts,
                                                         int* __restrict__ ffi,
                                                         float* __restrict__ fnpts,
                                                         float* __restrict__ fdist,
                                                         int* __restrict__ ffar) {
  __shared__ __align__(16) u16 As[128 * 32];
  __shared__ __align__(16) u16 Bs[128 * 32];
  const int wv = threadIdx.x >> 6, lane = threadIdx.x & 63;
  if (blockIdx.y == 0) {
    if (blockIdx.x < 8)
      fps_core<8, 2>(fpts, ffi, fnpts, 512, 128, blockIdx.x * 4 + wv, lane, 56, 78,
                     fdist, ffar);
    return;
  }
  const int y = blockIdx.y - 1;
  const int stage = y >> 3;
  const int mt = y & 7;
  const u16* A = Wa1 + (size_t)stage * 1024 * KP;
  const u16* B = WdT + (size_t)stage * NP0 * KP;
  u16* C = Wcomb + (size_t)stage * 1024 * KP;
  gemm_tile_body<1, 0>(A, B, C, KP, KP, KP, mt * 128, blockIdx.x * 128,
                       nullptr, 0, 0, As, Bs);
}

// ---------------- Z1 fused: fps0 [78,128) + Z1 GEMM (bf16 out) --------------
// y==0: fps | y in [1,129): 128 m-tiles (XCD-swizzled).
__global__ __launch_bounds__(256) void z1_fused_kernel(const u16* __restrict__ A,
                                                       const u16* __restrict__ Bt,
                                                       u16* __restrict__ C,
                                                       const float* __restrict__ fpts,
                                                       int* __restrict__ ffi,
                                                       float* __restrict__ fnpts,
                                                       float* __restrict__ fdist,
                                                       int* __restrict__ ffar) {
  const int t = threadIdx.x;
  const int lane = t & 63, wv = t >> 6;
  if (blockIdx.y == 0) {
    if (blockIdx.x < 8)
      fps_core<8, 2>(fpts, ffi, fnpts, 512, 128, blockIdx.x * 4 + wv, lane, 78, 128,
                     fdist, ffar);
    return;
  }
  __shared__ __align__(16) u16 As[128 * 32];
  __shared__ __align__(16) u16 Bs[128 * 32];
  const int g = ((int)blockIdx.y - 1) * 8 + blockIdx.x;
  const int xcd = g & 7;
  const int r = g >> 3;
  const int mt = xcd * 16 + (r >> 3);  // MT=128, cpx=16
  const int nt = r & 7;
  gemm_tile_body<1, 0>(A, Bt, C, KP, 1024, 1024, mt * 128, nt * 128,
                       nullptr, 0, 0, As, Bs);
}

// ---------------- general MFMA GEMM dispatch (Z2 + knn0) --------------------
template <int BF16OUT, int SWZ, int KNN_PPL, int IND>
__global__ __launch_bounds__(256) void gemm_bt_kernel(const u16* __restrict__ A,
                                                      const u16* __restrict__ Bt,
                                                      void* __restrict__ Cout,
                                                      int K, int ldc, int nvalid,
                                                      const int* __restrict__ find,
                                                      int iNp, int iS,
                                                      const float* __restrict__ kq,
                                                      const float* __restrict__ kr,
                                                      int* __restrict__ kidx,
                                                      int kNp, int kS, int kYoff) {
  const int tid = threadIdx.x;
  const int lane = tid & 63;
  const int wv = tid >> 6;
  if (KNN_PPL > 0 && (int)blockIdx.y >= kYoff) {
    int kb = ((int)blockIdx.y - kYoff) * gridDim.x + blockIdx.x;
    knn_core<KNN_PPL ? KNN_PPL : 1>(kq, kr, kidx, kNp, kS, kb * 4 + wv, lane);
    return;
  }
  __shared__ __align__(16) u16 As[128 * 32];
  __shared__ __align__(16) u16 Bs[128 * 32];
  int mt, nt;
  if (SWZ) {
    const int g = (int)blockIdx.y * gridDim.x + blockIdx.x;
    const int MT = (KNN_PPL > 0 ? kYoff : (int)gridDim.y);
    const int cpx = MT >> 3;
    const int xcd = g & 7;
    const int r = g >> 3;
    mt = xcd * cpx + (r >> 3);
    nt = r & 7;
  } else {
    mt = (int)blockIdx.y;
    nt = blockIdx.x;
  }
  gemm_tile_body<BF16OUT, IND>(A, Bt, Cout, K, ldc, nvalid, mt * 128, nt * 128,
                               find, iNp, iS, As, Bs);
}

// ---------------- stage-1 fused: Z1'(bf16) + Z2'(indirect) + knn1 -----------
// y in [0,32): Z1' tiles (swz MT=32) | y in [32,40): Z2' (IND) | y in [40,72): knn1
__global__ __launch_bounds__(256) void stage1_fused_kernel(const u16* __restrict__ X1bf,
                                                           const u16* __restrict__ Wcomb1,
                                                           const u16* __restrict__ Wa21,
                                                           u16* __restrict__ Z1,
                                                           float* __restrict__ Z2g,
                                                           const int* __restrict__ fi1,
                                                           const float* __restrict__ npts1,
                                                           const float* __restrict__ npts0,
                                                           int* __restrict__ idx1) {
  __shared__ __align__(16) u16 As[128 * 32];
  __shared__ __align__(16) u16 Bs[128 * 32];
  const int lane = threadIdx.x & 63, wv = threadIdx.x >> 6;
  if (blockIdx.y < 32) {
    const int g = (int)blockIdx.y * 8 + blockIdx.x;
    const int xcd = g & 7;
    const int r = g >> 3;
    const int mt = xcd * 4 + (r >> 3);  // MT=32, cpx=4
    const int nt = r & 7;
    gemm_tile_body<1, 0>(X1bf, Wcomb1, Z1, KP, 1024, 1024, mt * 128, nt * 128,
                         nullptr, 0, 0, As, Bs);
    return;
  }
  if (blockIdx.y < 40) {
    const int mt = (int)blockIdx.y - 32;
    const int nt = blockIdx.x;
    gemm_tile_body<0, 1>(X1bf, Wa21, Z2g, KP, 1024, 1024, mt * 128, nt * 128,
                         fi1, 128, 32, As, Bs);
    return;
  }
  const int kb = ((int)blockIdx.y - 40) * 8 + blockIdx.x;
  knn_core<2>(npts1, npts0, idx1, 128, 32, kb * 4 + wv, lane);
}

// ---------------- fused gather + relu + LN + mean_k -------------------------
// Wave-per-q, DPP add-scan LN, XCD-bijective swizzle. Z1 is bf16 (exact
// widening on read); Z2/czero fp32. FPS_PPL>0: first 8 blocks run fps_core.
template <int MODE, int FPS_PPL, int FPS_HS>
__global__ __launch_bounds__(256) void h_epilogue_kernel(const u16* __restrict__ Z1,
                                                         const float* __restrict__ Z2g,
                                                         const float* __restrict__ czero,
                                                         const int* __restrict__ idxK,
                                                         const int* __restrict__ fi,
                                                         const float* __restrict__ g,
                                                         const float* __restrict__ bb,
                                                         const float* __restrict__ npts,
                                                         void* __restrict__ outp,
                                                         int Np, int S, int cpx,
                                                         const float* __restrict__ fpts,
                                                         int* __restrict__ ffi,
                                                         float* __restrict__ fnpts,
                                                         int fNp, int fS) {
  const int t = threadIdx.x;
  const int lane = t & 63, wv = t >> 6;
  if (FPS_PPL > 0 && blockIdx.x < 8) {
    fps_core<FPS_PPL ? FPS_PPL : 1, FPS_HS>(fpts, ffi, fnpts, fNp, fS,
                                            blockIdx.x * 4 + wv, lane, 0, fS,
                                            nullptr, nullptr);
    return;
  }
  const int bid = blockIdx.x - (FPS_PPL > 0 ? 8 : 0);
  const int sw = (bid & 7) * cpx + (bid >> 3);  // XCD-contiguous q ranges
  const int q = sw * 4 + wv;
  const int b = q / S;
  const int fiv = fi[q];
  const float* z2 = Z2g + (size_t)q * 1024;
  const u16* zf = Z1 + ((size_t)b * Np + fiv) * 1024;
  const int ch = lane * 4;  // + j*256

  f32x4 base[4], gv[4], bv[4], acc[4];
  #pragma unroll
  for (int j = 0; j < 4; ++j) {
    f32x4 a = *(const f32x4*)(z2 + j * 256 + ch);
    f32x4 c = *(const f32x4*)(czero + j * 256 + ch);
    u16x4 f = *(const u16x4*)(zf + j * 256 + ch);
    #pragma unroll
    for (int c2 = 0; c2 < 4; ++c2) base[j][c2] = a[c2] + c[c2] - bf2f(f[c2]);
    gv[j] = *(const f32x4*)(g + j * 256 + ch);
    bv[j] = *(const f32x4*)(bb + j * 256 + ch);
    #pragma unroll
    for (int c2 = 0; c2 < 4; ++c2) acc[j][c2] = 0.f;
  }
  int nk = 0;
  if (lane < 24) nk = idxK[(size_t)q * 24 + lane];

  for (int k = 0; k < 24; ++k) {
    const int n = __builtin_amdgcn_readlane(nk, k);
    const u16* zr = Z1 + ((size_t)b * Np + n) * 1024;
    f32x4 v[4];
    float s1 = 0.f, s2 = 0.f;
    #pragma unroll
    for (int j = 0; j < 4; ++j) {
      u16x4 r = *(const u16x4*)(zr + j * 256 + ch);
      #pragma unroll
      for (int c2 = 0; c2 < 4; ++c2) {
        float x = fmaxf(bf2f(r[c2]) + base[j][c2], 0.f);
        v[j][c2] = x;
        s1 += x;
        s2 += x * x;
      }
    }
    s1 = wave_sum63(s1);
    s2 = wave_sum63(s2);
    const float S1 = rl_f(s1, 63);
    const float S2 = rl_f(s2, 63);
    const float m = S1 * (1.f / 1024.f);
    const float var = S2 * (1.f / 1024.f) - m * m;
    const float rs = rsqrtf(var + 1e-5f);
    #pragma unroll
    for (int j = 0; j < 4; ++j)
      #pragma unroll
      for (int c2 = 0; c2 < 4; ++c2)
        acc[j][c2] += (v[j][c2] - m) * rs * gv[j][c2] + bv[j][c2];
  }

  u16x4 o4[4];
  #pragma unroll
  for (int j = 0; j < 4; ++j)
    #pragma unroll
    for (int c2 = 0; c2 < 4; ++c2) o4[j][c2] = f2bf(acc[j][c2] * (1.f / 24.f));

  if (MODE == 0) {
    u16* X = (u16*)outp;
    size_t ro = (size_t)q * KP;
    #pragma unroll
    for (int j = 0; j < 4; ++j) *(u16x4*)(X + ro + j * 256 + ch) = o4[j];
    if (lane == 0) {
      X[ro + 1024] = f2bf(npts[(size_t)q * 2]);
      X[ro + 1025] = f2bf(npts[(size_t)q * 2 + 1]);
    }
    if (lane < 15) ((u32*)(X + ro + 1026))[lane] = 0;
  } else {
    u16* X = (u16*)outp + (size_t)q * 1024;
    #pragma unroll
    for (int j = 0; j < 4; ++j) *(u16x4*)(X + j * 256 + ch) = o4[j];
  }
}

// ---------------- MLP MFMA GEMM (fp32 A): P[blk] = W_tile(->bf16) @ Fb^T ----
template <int KSBITS, int NST>
__global__ __launch_bounds__(256, 4) void mlp_mfma_kernel(const float* __restrict__ W,
                                                          const u16* __restrict__ Fb,
                                                          float* __restrict__ P, int K) {
  __shared__ __align__(16) float Asf[128 * 32];
  __shared__ __align__(16) u16 Fsb[32 * 40];
  const int tid = threadIdx.x, lane = tid & 63, wv = tid >> 6;
  const int ot = blockIdx.x >> KSBITS;
  const int ks = blockIdx.x & ((1 << KSBITS) - 1);
  const int m0 = ot * 128;
  const int k0b = ks * (NST * 32);
  const int arow = lane >> 3;
  const int agrp = lane & 7;
  const int rf = lane & 15, quad = lane >> 4;

  f32x4 acc[2][2];
  #pragma unroll
  for (int i = 0; i < 2; ++i)
    #pragma unroll
    for (int j = 0; j < 2; ++j)
      #pragma unroll
      for (int c = 0; c < 4; ++c) acc[i][j][c] = 0.f;

  for (int st = 0; st < NST; ++st) {
    const int k0 = k0b + st * 32;
    #pragma unroll
    for (int i = 0; i < 4; ++i) {
      const int row = wv * 32 + i * 8 + arow;
      const int g = agrp ^ (row & 7);
      const float* ga = W + (size_t)(m0 + row) * K + k0 + g * 4;
      __builtin_amdgcn_global_load_lds((gvp)ga, (svp)(Asf + (wv * 32 + i * 8) * 32), 16, 0, 0);
    }
    if (tid < 128) {
      const int fr = tid >> 2, fc = (tid & 3) * 8;
      u32x4 tmp = *(const u32x4*)(Fb + (size_t)fr * K + k0 + fc);
      *(u32x4*)(Fsb + fr * 40 + fc) = tmp;
    }
    __syncthreads();
    bf16x8 bfr[2];
    #pragma unroll
    for (int ni = 0; ni < 2; ++ni)
      bfr[ni] = *(const bf16x8*)(Fsb + (ni * 16 + rf) * 40 + quad * 8);
    #pragma unroll
    for (int mi = 0; mi < 2; ++mi) {
      const float* ap = Asf + (size_t)(wv * 32 + mi * 16 + rf) * 32;
      f32x4 a0 = *(const f32x4*)(ap + (((quad * 2) ^ (rf & 7)) * 4));
      f32x4 a1 = *(const f32x4*)(ap + (((quad * 2 + 1) ^ (rf & 7)) * 4));
      union { bf16x8 v; u16 h[8]; } af;
      #pragma unroll
      for (int c = 0; c < 4; ++c) { af.h[c] = f2bf(a0[c]); af.h[4 + c] = f2bf(a1[c]); }
      #pragma unroll
      for (int ni = 0; ni < 2; ++ni)
        acc[mi][ni] = __builtin_amdgcn_mfma_f32_16x16x32_bf16(af.v, bfr[ni], acc[mi][ni], 0, 0, 0);
    }
    __syncthreads();
  }

  float* Pb = P + (size_t)blockIdx.x * 4096;
  const int rq = (lane >> 4) * 4, cf = lane & 15;
  #pragma unroll
  for (int mi = 0; mi < 2; ++mi)
    #pragma unroll
    for (int ni = 0; ni < 2; ++ni)
      #pragma unroll
      for (int r = 0; r < 4; ++r)
        Pb[(wv * 32 + mi * 16 + rq + r) * 32 + ni * 16 + cf] = acc[mi][ni][r];
}

// ---------------- K-split partial reductions (bias fused) -------------------
__global__ __launch_bounds__(256) void reduce_flat_kernel(const float* __restrict__ P,
                                                          const float* __restrict__ bias,
                                                          u16* __restrict__ x1bf) {
  int idx = blockIdx.x * 256 + threadIdx.x;  // 32768
  int o = idx >> 5, b = idx & 31;
  float s = bias[o];
  const float* p = P + ((size_t)(o >> 7) * 64) * 4096 + (o & 127) * 32 + b;
  #pragma unroll 8
  for (int ks = 0; ks < 64; ++ks) s += p[(size_t)ks * 4096];
  x1bf[(size_t)b * 1024 + o] = f2bf(s);
}

__global__ __launch_bounds__(256) void reduce_dim_kernel(const float* __restrict__ P,
                                                         const float* __restrict__ bias,
                                                         float* __restrict__ out) {
  int idx = blockIdx.x * 256 + threadIdx.x;  // 131072
  int o = idx >> 5, b = idx & 31;
  float s = bias[o];
  const float* p = P + ((size_t)(o >> 7) * 8) * 4096 + (o & 127) * 32 + b;
  #pragma unroll
  for (int ks = 0; ks < 8; ++ks) s += p[(size_t)ks * 4096];
  out[(size_t)b * 4096 + o] = s;
}

// ---------------------------------------------------------------------------
extern "C" void kernel_launch(void* const* d_in, const int* in_sizes, int n_in,
                              void* d_out, int out_size, void* d_ws, size_t ws_size,
                              hipStream_t stream) {
  const float* fmap  = (const float*)d_in[0];
  const float* pts   = (const float*)d_in[1];
  const float* Wdiff = (const float*)d_in[2];
  const float* bdiff = (const float*)d_in[3];
  const float* Wagg  = (const float*)d_in[4];
  const float* bagg  = (const float*)d_in[5];
  const float* lng   = (const float*)d_in[6];
  const float* lnb   = (const float*)d_in[7];
  const float* Wflat = (const float*)d_in[8];
  const float* bflat = (const float*)d_in[9];
  const float* Wdim  = (const float*)d_in[10];
  const float* bdim  = (const float*)d_in[11];
  float* out = (float*)d_out;

  char* w = (char*)d_ws;
  size_t off = 0;
  auto alloc = [&](size_t n) { char* p = w + off; off += (n + 255) & ~(size_t)255; return p; };

  u16* Z1    = (u16*)alloc(16384ull * 1024 * 2);      // 33.5 MB bf16
  float* Z2g   = (float*)alloc(4096ull * 1024 * 4);   // 16.8 MB
  u16* Xbf0  = (u16*)alloc(16384ull * KP * 2);
  u16* X1bf  = (u16*)alloc(4096ull * KP * 2);
  u16* WdT   = (u16*)alloc(2ull * NP0 * KP * 2);      // both stages
  u16* Wa1   = (u16*)alloc(2ull * 1024 * KP * 2);
  u16* Wa2   = (u16*)alloc(2ull * 1024 * KP * 2);
  u16* Wcomb = (u16*)alloc(2ull * 1024 * KP * 2);
  float* czero = (float*)alloc(2 * 1024 * 4);
  int* fi0   = (int*)alloc(32 * 128 * 4);
  int* fi1   = (int*)alloc(32 * 32 * 4);
  int* idx0  = (int*)alloc(32 * 128 * 24 * 4);
  int* idx1  = (int*)alloc(32 * 32 * 24 * 4);
  float* npts0 = (float*)alloc(32 * 128 * 2 * 4);
  float* npts1 = (float*)alloc(32 * 32 * 2 * 4);
  u16* fea2bf = (u16*)alloc(32ull * 32768 * 2);       // 2 MB bf16
  u16* x1bf   = (u16*)alloc(32ull * 1024 * 2);        // 64 KB bf16
  float* Pf   = (float*)alloc(512ull * 4096 * 4);     // 8 MB partials (flat)
  float* Pd   = (float*)alloc(256ull * 4096 * 4);     // 4 MB partials (dim)
  float* fdist = (float*)alloc(32ull * 512 * 4);      // fps0 dist state
  int* ffar    = (int*)alloc(32 * 4);                 // fps0 far state

  // D1: stage-0 inputs + fps0 [0,32)
  bilinear_fused_kernel<<<dim3(32, 33), 256, 0, stream>>>(fmap, pts, Xbf0, fi0, npts0,
                                                          fdist, ffar);
  // D2: merged weight prep (both stages) + fps0 [32,56)
  prep_merged_kernel<<<4432, 256, 0, stream>>>(Wdiff, WdT, Wagg, bdiff, bagg,
                                               Wa1, Wa2, czero, pts, fi0, npts0,
                                               fdist, ffar);
  // D3: both Wcomb GEMMs + fps0 [56,78)
  wcomb_dual_kernel<<<dim3(9, 17), 256, 0, stream>>>(Wa1, WdT, Wcomb, pts, fi0, npts0,
                                                     fdist, ffar);
  // D4: Z1 (stage0, bf16 out) + fps0 [78,128)
  z1_fused_kernel<<<dim3(8, 129), 256, 0, stream>>>(Xbf0, Wcomb, Z1,
                                                    pts, fi0, npts0, fdist, ffar);
  // D5: Z2 (A rows via fi0) + knn0
  gemm_bt_kernel<0, 1, 8, 1><<<dim3(8, 160), 256, 0, stream>>>(
      Xbf0, Wa2, Z2g, KP, 1024, 1024,
      fi0, 512, 128,
      npts0, pts, idx0, 512, 128, 32);
  // D6: h_epilogue0 + fps1 full [0,32)
  h_epilogue_kernel<0, 2, 1><<<1032, 256, 0, stream>>>(
      Z1, Z2g, czero, idx0, fi0, lng, lnb, npts0, X1bf, 512, 128, 128,
      npts0, fi1, npts1, 128, 32);
  // D7: stage-1 fused (Z1'(bf16) + Z2' + knn1)
  stage1_fused_kernel<<<dim3(8, 72), 256, 0, stream>>>(
      X1bf, Wcomb + 1024ull * KP, Wa2 + 1024ull * KP, Z1, Z2g, fi1,
      npts1, npts0, idx1);
  // D8: h_epilogue1
  h_epilogue_kernel<1, 0, 1><<<256, 256, 0, stream>>>(
      Z1, Z2g, czero + 1024, idx1, fi1, lng + 1024, lnb + 1024, npts1, fea2bf,
      128, 32, 32, nullptr, nullptr, nullptr, 0, 0);

  // D9-12: final MLP (MFMA, K-split partials + reduce)
  mlp_mfma_kernel<6, 16><<<512, 256, 0, stream>>>(Wflat, fea2bf, Pf, 32768);
  reduce_flat_kernel<<<128, 256, 0, stream>>>(Pf, bflat, x1bf);
  mlp_mfma_kernel<3, 4><<<256, 256, 0, stream>>>(Wdim, x1bf, Pd, 1024);
  reduce_dim_kernel<<<512, 256, 0, stream>>>(Pd, bdim, out);
}

// Round 14
// 508.554 us; speedup vs baseline: 1.0251x; 1.0054x over previous
//
#include <hip/hip_runtime.h>

// ---------------------------------------------------------------------------
// GeoRegionSampler: restructured pipeline
//   X = [bilinear_fea | pts] (bf16, padded 1026->1056)
//   Wcomb = Wa1 @ Wd ; Z1 = X @ Wcomb^T (bf16); Z2 = X[fi] @ Wa2^T (bf16)
//   h = relu(Z1[idx]-Z1[fi]+Z2+czero) -> LN -> mean_k (wave-per-q, DPP)
//   final MLP: MFMA GEMMs + K-split reduce.
// R18 (this round): Z2 stored bf16 (same proven move as R15's Z1-bf16).
//   R17 locked the session-best structure (511.3us). Z2g write+read was
//   33.6MB fp32 round-trip; bf16 halves it (~4-5us). Numerics: absmax
//   was bit-identical after Z1-bf16 (0.0625), so the third rounding in
//   the same pre-LN sum should be absorbed. Parameter-level change only
//   (BF16OUT=1 on the two Z2 GEMMs + u16 reads in epilogue) -- no
//   schedule/occupancy/LDS changes (the classes that regressed).
//   Carried: noinline fps/knn cores, bf16 Z1, fi-indirect Z2, wave-per-q
//   DPP epilogue, XCD-bijective remap, fp32 mlp_mfma, R15 4-way fps split.
// ---------------------------------------------------------------------------

typedef float f32x4 __attribute__((ext_vector_type(4)));
typedef short bf16x8 __attribute__((ext_vector_type(8)));
typedef unsigned short u16;
typedef u16 u16x4 __attribute__((ext_vector_type(4)));
typedef unsigned int u32;
typedef u32 u32x4 __attribute__((ext_vector_type(4)));
typedef unsigned long long u64;

typedef const void __attribute__((address_space(1)))* gvp;
typedef void __attribute__((address_space(3)))* svp;

__device__ __forceinline__ u16 f2bf(float f) {
  union { float f; u32 u; } x; x.f = f;
  u32 r = x.u + 0x7fffu + ((x.u >> 16) & 1u);
  return (u16)(r >> 16);
}

__device__ __forceinline__ float bf2f(u16 h) {
  union { u32 u; float f; } x; x.u = ((u32)h) << 16;
  return x.f;
}

#define KP 1056   // padded Dp (1026 -> 33*32)
#define NP0 1152  // padded N for weight-combine GEMM (9*128)

// ---- DPP cross-lane helpers (VALU pipe) -----------------------------------
__device__ __forceinline__ float rl_f(float v, int lane) {
  return __int_as_float(__builtin_amdgcn_readlane(__float_as_int(v), lane));
}

template <int CTRL>
__device__ __forceinline__ float dpp_fmax(float v) {
  float o = __int_as_float(__builtin_amdgcn_update_dpp(
      (int)0xff800000 /* -inf */, __float_as_int(v), CTRL, 0xf, 0xf, false));
  return fmaxf(v, o);
}

template <int CTRL>
__device__ __forceinline__ float dpp_fmin(float v) {
  float o = __int_as_float(__builtin_amdgcn_update_dpp(
      0x7f800000 /* +inf */, __float_as_int(v), CTRL, 0xf, 0xf, false));
  return fminf(v, o);
}

template <int CTRL>
__device__ __forceinline__ float dpp_add(float v) {
  float o = __int_as_float(__builtin_amdgcn_update_dpp(
      0, __float_as_int(v), CTRL, 0xf, 0xf, false));
  return v + o;
}

__device__ __forceinline__ float wave_fmax63(float v) {
  v = dpp_fmax<0x111>(v);
  v = dpp_fmax<0x112>(v);
  v = dpp_fmax<0x114>(v);
  v = dpp_fmax<0x118>(v);
  v = dpp_fmax<0x142>(v);
  v = dpp_fmax<0x143>(v);
  return rl_f(v, 63);
}

__device__ __forceinline__ float wave_fmin63(float v) {
  v = dpp_fmin<0x111>(v);
  v = dpp_fmin<0x112>(v);
  v = dpp_fmin<0x114>(v);
  v = dpp_fmin<0x118>(v);
  v = dpp_fmin<0x142>(v);
  v = dpp_fmin<0x143>(v);
  return rl_f(v, 63);
}

__device__ __forceinline__ float wave_sum63(float v) {
  v = dpp_add<0x111>(v);
  v = dpp_add<0x112>(v);
  v = dpp_add<0x114>(v);
  v = dpp_add<0x118>(v);
  v = dpp_add<0x142>(v);
  v = dpp_add<0x143>(v);
  return v;
}

// ---------------- FPS core: one wave per batch, bit-exact -------------------
// Resumable [s0,s1); dist/far state spilled as raw fp32 bits (exact).
// Emits fi AND npts (coords copied bit-exact from pts) for its own range.
// noinline: keeps this path's regalloc out of the host GEMM kernel's body.
template <int PPL, int HS>
__device__ __attribute__((noinline)) void fps_core(
    const float* __restrict__ pts, int* __restrict__ fi,
    float* __restrict__ npts,
    int Np, int S, int b, int lane, int s0, int s1,
    float* __restrict__ dsave, int* __restrict__ fsave) {
  #pragma clang fp contract(off)
  float px[PPL], py[PPL], dist[PPL];
  #pragma unroll
  for (int j = 0; j < PPL; ++j) {
    int n = j * 64 + lane;
    px[j] = pts[((size_t)b * Np + n) * 2];
    py[j] = pts[((size_t)b * Np + n) * 2 + 1];
  }
  int far; float cx, cy;
  if (s0 == 0) {
    #pragma unroll
    for (int j = 0; j < PPL; ++j) dist[j] = 1e10f;
    far = 0;
    cx = rl_f(px[0], 0);
    cy = rl_f(py[0], 0);
  } else {
    #pragma unroll
    for (int j = 0; j < PPL; ++j) dist[j] = dsave[(size_t)b * Np + j * 64 + lane];
    far = fsave[b];
    cx = pts[((size_t)b * Np + far) * 2];
    cy = pts[((size_t)b * Np + far) * 2 + 1];
  }
  int hist[HS];
  #pragma unroll
  for (int h = 0; h < HS; ++h) hist[h] = 0;
  for (int s = s0; s < s1; ++s) {
    #pragma unroll
    for (int h = 0; h < HS; ++h)
      if ((s >> 6) == h && (s & 63) == lane) hist[h] = far;
    float bv = -1.f; int bi = 0; float bx = 0.f, by = 0.f;
    #pragma unroll
    for (int j = 0; j < PPL; ++j) {
      float dx = px[j] - cx, dy = py[j] - cy;
      float d = dx * dx + dy * dy;
      float nd = fminf(dist[j], d);
      dist[j] = nd;
      if (nd > bv) { bv = nd; bi = j * 64 + lane; bx = px[j]; by = py[j]; }
    }
    float smax = wave_fmax63(bv);
    u64 mask = __ballot(bv == smax);
    int L = __builtin_ctzll(mask);
    int fidx = __builtin_amdgcn_readlane(bi, L);
    float fx = rl_f(bx, L), fy = rl_f(by, L);
    u64 rest = mask & (mask - 1);
    if (__builtin_expect(rest != 0, 0)) {
      // rare: multiple lanes hold the max value -> exact min-index tiebreak
      while (rest) {
        int L2 = __builtin_ctzll(rest);
        int c = __builtin_amdgcn_readlane(bi, L2);
        if (c < fidx) {
          fidx = c; fx = rl_f(bx, L2); fy = rl_f(by, L2);
        }
        rest &= rest - 1;
      }
    }
    far = fidx; cx = fx; cy = fy;
  }
  if (s1 < S) {
    #pragma unroll
    for (int j = 0; j < PPL; ++j) dsave[(size_t)b * Np + j * 64 + lane] = dist[j];
    if (lane == 0) fsave[b] = far;
  }
  #pragma unroll
  for (int h = 0; h < HS; ++h) {
    int s = h * 64 + lane;
    if (s >= s0 && s < s1) {
      int hv = hist[h];
      fi[b * S + s] = hv;
      npts[(size_t)(b * S + s) * 2]     = pts[((size_t)b * Np + hv) * 2];
      npts[(size_t)(b * S + s) * 2 + 1] = pts[((size_t)b * Np + hv) * 2 + 1];
    }
  }
}

// ---------------- kNN core: one wave per q, bit-exact -----------------------
template <int PPL>
__device__ __attribute__((noinline)) void knn_core(
    const float* __restrict__ qpts,
    const float* __restrict__ rpts,
    int* __restrict__ idxK, int Np, int S, int q, int lane) {
  #pragma clang fp contract(off)
  int b = q / S;
  float ax = qpts[(size_t)q * 2], ay = qpts[(size_t)q * 2 + 1];
  float a2 = ax * ax + ay * ay;
  float d2[PPL];
  #pragma unroll
  for (int j = 0; j < PPL; ++j) {
    int n = j * 64 + lane;
    float bx = rpts[((size_t)b * Np + n) * 2];
    float by = rpts[((size_t)b * Np + n) * 2 + 1];
    float b2 = bx * bx + by * by;
    float dot = ax * bx + ay * by;
    float t = a2 + b2;
    float m2 = 2.f * dot;
    d2[j] = t - m2;
  }
  int kreg = 0;
  for (int k = 0; k < 24; ++k) {
    float bv = 3.4e38f; int bi = 1 << 30;
    #pragma unroll
    for (int j = 0; j < PPL; ++j)
      if (d2[j] < bv) { bv = d2[j]; bi = j * 64 + lane; }
    float smin = wave_fmin63(bv);
    u64 mask = __ballot(bv == smin);
    int L = __builtin_ctzll(mask);
    int bs = __builtin_amdgcn_readlane(bi, L);
    u64 rest = mask & (mask - 1);
    if (__builtin_expect(rest != 0, 0)) {
      while (rest) {
        int L2 = __builtin_ctzll(rest);
        int c = __builtin_amdgcn_readlane(bi, L2);
        if (c < bs) bs = c;
        rest &= rest - 1;
      }
    }
    if (lane == k) kreg = bs;
    #pragma unroll
    for (int j = 0; j < PPL; ++j)
      if (j * 64 + lane == bs) d2[j] = 3.4e38f;
  }
  if (lane < 24) idxK[(size_t)q * 24 + lane] = kreg;
}

// ---------------- GEMM tile body (shared by all MFMA GEMMs) -----------------
// IND: A rows indexed via find[] (q -> b*iNp + find[q]); C rows stay direct.
// LDS: both-sides XOR swizzle on 16B slots (linear dest for global_load_lds).
template <int BF16OUT, int IND>
__device__ __forceinline__ void gemm_tile_body(const u16* __restrict__ A,
                                               const u16* __restrict__ Bt,
                                               void* __restrict__ Cout,
                                               int K, int ldc, int nvalid,
                                               int m0, int n0,
                                               const int* __restrict__ find,
                                               int iNp, int iS,
                                               u16* __restrict__ As,
                                               u16* __restrict__ Bs) {
  const int tid = threadIdx.x;
  const int lane = tid & 63;
  const int wv = tid >> 6;
  const int wm = (wv >> 1) * 64;
  const int wn = (wv & 1) * 64;

  f32x4 acc[4][4];
  #pragma unroll
  for (int i = 0; i < 4; ++i)
    #pragma unroll
    for (int j = 0; j < 4; ++j)
      #pragma unroll
      for (int c = 0; c < 4; ++c) acc[i][j][c] = 0.f;

  const int ch0 = wv * 2;
  const int rin = lane >> 2;
  const int slot = lane & 3;
  const int cin = (slot ^ (rin & 3) ^ ((rin >> 2) & 3)) * 8;  // pre-swizzled src col

  size_t aro[2];
  #pragma unroll
  for (int i = 0; i < 2; ++i) {
    const int row = (ch0 + i) * 16 + rin;
    if (IND) {
      const int q = m0 + row;
      aro[i] = (size_t)(q / iS) * iNp + find[q];
    } else {
      aro[i] = (size_t)(m0 + row);
    }
  }

  for (int k0 = 0; k0 < K; k0 += 32) {
    #pragma unroll
    for (int i = 0; i < 2; ++i) {
      const int ch = ch0 + i;
      const int row = ch * 16 + rin;
      const u16* ga = A + aro[i] * K + (k0 + cin);
      const u16* gb = Bt + (size_t)(n0 + row) * K + (k0 + cin);
      __builtin_amdgcn_global_load_lds((gvp)ga, (svp)(As + ch * 512), 16, 0, 0);
      __builtin_amdgcn_global_load_lds((gvp)gb, (svp)(Bs + ch * 512), 16, 0, 0);
    }
    __syncthreads();
    const int rf = lane & 15;
    const int quad = lane >> 4;
    const int qs = (quad ^ (rf & 3) ^ ((rf >> 2) & 3)) * 8;  // swizzled read slot
    bf16x8 af[4], bfv[4];
    #pragma unroll
    for (int mi = 0; mi < 4; ++mi)
      af[mi] = *(const bf16x8*)(As + (wm + mi * 16 + rf) * 32 + qs);
    #pragma unroll
    for (int ni = 0; ni < 4; ++ni)
      bfv[ni] = *(const bf16x8*)(Bs + (wn + ni * 16 + rf) * 32 + qs);
    #pragma unroll
    for (int mi = 0; mi < 4; ++mi)
      #pragma unroll
      for (int ni = 0; ni < 4; ++ni)
        acc[mi][ni] = __builtin_amdgcn_mfma_f32_16x16x32_bf16(af[mi], bfv[ni], acc[mi][ni], 0, 0, 0);
    __syncthreads();
  }

  const int rq = (lane >> 4) * 4;
  const int cf = lane & 15;
  #pragma unroll
  for (int mi = 0; mi < 4; ++mi) {
    #pragma unroll
    for (int ni = 0; ni < 4; ++ni) {
      const int col = n0 + wn + ni * 16 + cf;
      #pragma unroll
      for (int r = 0; r < 4; ++r) {
        const int row = m0 + wm + mi * 16 + rq + r;
        const float v = acc[mi][ni][r];
        if (BF16OUT) {
          if (col < nvalid) ((u16*)Cout)[(size_t)row * ldc + col] = f2bf(v);
        } else {
          ((float*)Cout)[(size_t)row * ldc + col] = v;
        }
      }
    }
  }
}

// ------- fused bilinear + fps0 segment [0,32) (y==0 row) -------------------
__global__ __launch_bounds__(256, 2) void bilinear_fused_kernel(const float* __restrict__ fmap,
                                                                const float* __restrict__ pts,
                                                                u16* __restrict__ X,
                                                                int* __restrict__ fi0,
                                                                float* __restrict__ npts0,
                                                                float* __restrict__ fdist,
                                                                int* __restrict__ ffar) {
  if (blockIdx.y == 0) {
    if (blockIdx.x < 8)
      fps_core<8, 2>(pts, fi0, npts0, 512, 128, blockIdx.x * 4 + (threadIdx.x >> 6),
                     threadIdx.x & 63, 0, 32, fdist, ffar);
    return;
  }
  __shared__ float fmS[32][580];
  const int ct = blockIdx.x, b = blockIdx.y - 1;
  const int t = threadIdx.x;
  const float* src = fmap + ((size_t)b * 1024 + ct * 32) * 576;
  const int tr = t >> 3, ti = t & 7;
  #pragma unroll
  for (int j = 0; j < 18; ++j) {
    int c4 = j * 8 + ti;
    *(f32x4*)&fmS[tr][c4 * 4] = *(const f32x4*)(src + (size_t)tr * 576 + c4 * 4);
  }
  __syncthreads();
  #pragma unroll
  for (int pass = 0; pass < 2; ++pass) {
    const int n = pass * 256 + t;
    const int pidx = b * 512 + n;
    float p0 = pts[(size_t)pidx * 2], p1 = pts[(size_t)pidx * 2 + 1];
    float gy = p0 * 23.f, gx = p1 * 23.f;
    float y0f = floorf(gy), x0f = floorf(gx);
    float wy = gy - y0f, wx = gx - x0f;
    int y0 = (int)y0f; y0 = y0 < 0 ? 0 : (y0 > 23 ? 23 : y0);
    int x0 = (int)x0f; x0 = x0 < 0 ? 0 : (x0 > 23 ? 23 : x0);
    int y1 = y0 + 1 > 23 ? 23 : y0 + 1;
    int x1 = x0 + 1 > 23 ? 23 : x0 + 1;
    float w00 = (1.f - wy) * (1.f - wx), w01 = (1.f - wy) * wx;
    float w10 = wy * (1.f - wx), w11 = wy * wx;
    const int i00 = y0 * 24 + x0, i01 = y0 * 24 + x1;
    const int i10 = y1 * 24 + x0, i11 = y1 * 24 + x1;
    size_t ro = (size_t)pidx * KP + ct * 32;
    #pragma unroll
    for (int cq = 0; cq < 8; ++cq) {
      u16x4 o4;
      #pragma unroll
      for (int cc = 0; cc < 4; ++cc) {
        int c = cq * 4 + cc;
        float v = w00 * fmS[c][i00] + w01 * fmS[c][i01] +
                  w10 * fmS[c][i10] + w11 * fmS[c][i11];
        o4[cc] = f2bf(v);
      }
      *(u16x4*)(X + ro + cq * 4) = o4;
    }
    if (ct == 31) {
      size_t rb = (size_t)pidx * KP;
      X[rb + 1024] = f2bf(p0);
      X[rb + 1025] = f2bf(p1);
      #pragma unroll
      for (int z = 0; z < 15; ++z) ((u32*)(X + rb + 1026))[z] = 0;
    }
  }
}

// ---------------- merged prep: wd_transpose + waggcz + fps0 [32,56) ---------
// blocks: [0,8) fps | [8, 8+2376) wdT (33 x 36 x 2) | [2384, 4432) waggcz
__global__ __launch_bounds__(256) void prep_merged_kernel(const float* __restrict__ Wd,
                                                          u16* __restrict__ WdT,
                                                          const float* __restrict__ Wagg,
                                                          const float* __restrict__ bdiff,
                                                          const float* __restrict__ bagg,
                                                          u16* __restrict__ Wa1,
                                                          u16* __restrict__ Wa2,
                                                          float* __restrict__ czero,
                                                          const float* __restrict__ fpts,
                                                          int* __restrict__ ffi,
                                                          float* __restrict__ fnpts,
                                                          float* __restrict__ fdist,
                                                          int* __restrict__ ffar) {
  __shared__ float tbuf[32][33];
  __shared__ float red[4];
  const int bid = blockIdx.x;
  const int t = threadIdx.x;
  const int lane = t & 63, wv = t >> 6;
  if (bid < 8) {
    fps_core<8, 2>(fpts, ffi, fnpts, 512, 128, bid * 4 + wv, lane, 32, 56, fdist, ffar);
    return;
  }
  if (bid < 8 + 2376) {
    const int i = bid - 8;
    const int z = i / 1188;
    const int r = i % 1188;
    const int bx = r % 33, by = r / 33;
    const float* Wds = Wd + (size_t)z * 1026 * 1026;
    u16* WdTs = WdT + (size_t)z * NP0 * KP;
    int tx = t & 31, ty = t >> 5;
    int ot = bx * 32, dt = by * 32;
    #pragma unroll
    for (int j = 0; j < 4; ++j) {
      int o = ot + ty + 8 * j, d = dt + tx;
      tbuf[ty + 8 * j][tx] = (o < 1026 && d < 1026) ? Wds[(size_t)o * 1026 + d] : 0.f;
    }
    __syncthreads();
    #pragma unroll
    for (int j = 0; j < 4; ++j) {
      int d = dt + ty + 8 * j, o = ot + tx;
      if (o < KP) WdTs[(size_t)d * KP + o] = f2bf(tbuf[tx][ty + 8 * j]);
    }
    return;
  }
  const int i = bid - (8 + 2376);
  const int stage = i >> 10, c = i & 1023;
  const float* row = Wagg + (size_t)stage * 1024 * 2052 + (size_t)c * 2052;
  const float* bd = bdiff + stage * 1026;
  u16* wa1 = Wa1 + (size_t)stage * 1024 * KP + (size_t)c * KP;
  u16* wa2 = Wa2 + (size_t)stage * 1024 * KP + (size_t)c * KP;
  float acc = 0.f;
  for (int d = t; d < KP; d += 256) {
    if (d < 1026) {
      float v1 = row[d];
      float v2 = row[1026 + d];
      wa1[d] = f2bf(v1);
      wa2[d] = f2bf(v2);
      acc += bd[d] * v1;
    } else {
      wa1[d] = 0;
      wa2[d] = 0;
    }
  }
  float s = wave_sum63(acc);
  if (lane == 63) red[wv] = s;
  __syncthreads();
  if (t == 0)
    czero[(size_t)stage * 1024 + c] = red[0] + red[1] + red[2] + red[3] + bagg[stage * 1024 + c];
}

// Both Wcomb GEMMs (stage0 y in [1,8], stage1 y in [9,16]) + fps0 [56,78).
__global__ __launch_bounds__(256) void wcomb_dual_kernel(const u16* __restrict__ Wa1,
                                                         const u16* __restrict__ WdT,
                                                         u16* __restrict__ Wcomb,
                                                         const float* __restrict__ fpts,
                                                         int* __restrict__ ffi,
                                                         float* __restrict__ fnpts,
                                                         float* __restrict__ fdist,
                                                         int* __restrict__ ffar) {
  __shared__ __align__(16) u16 As[128 * 32];
  __shared__ __align__(16) u16 Bs[128 * 32];
  const int wv = threadIdx.x >> 6, lane = threadIdx.x & 63;
  if (blockIdx.y == 0) {
    if (blockIdx.x < 8)
      fps_core<8, 2>(fpts, ffi, fnpts, 512, 128, blockIdx.x * 4 + wv, lane, 56, 78,
                     fdist, ffar);
    return;
  }
  const int y = blockIdx.y - 1;
  const int stage = y >> 3;
  const int mt = y & 7;
  const u16* A = Wa1 + (size_t)stage * 1024 * KP;
  const u16* B = WdT + (size_t)stage * NP0 * KP;
  u16* C = Wcomb + (size_t)stage * 1024 * KP;
  gemm_tile_body<1, 0>(A, B, C, KP, KP, KP, mt * 128, blockIdx.x * 128,
                       nullptr, 0, 0, As, Bs);
}

// ---------------- Z1 fused: fps0 [78,128) + Z1 GEMM (bf16 out) --------------
// y==0: fps | y in [1,129): 128 m-tiles (XCD-swizzled).
__global__ __launch_bounds__(256) void z1_fused_kernel(const u16* __restrict__ A,
                                                       const u16* __restrict__ Bt,
                                                       u16* __restrict__ C,
                                                       const float* __restrict__ fpts,
                                                       int* __restrict__ ffi,
                                                       float* __restrict__ fnpts,
                                                       float* __restrict__ fdist,
                                                       int* __restrict__ ffar) {
  const int t = threadIdx.x;
  const int lane = t & 63, wv = t >> 6;
  if (blockIdx.y == 0) {
    if (blockIdx.x < 8)
      fps_core<8, 2>(fpts, ffi, fnpts, 512, 128, blockIdx.x * 4 + wv, lane, 78, 128,
                     fdist, ffar);
    return;
  }
  __shared__ __align__(16) u16 As[128 * 32];
  __shared__ __align__(16) u16 Bs[128 * 32];
  const int g = ((int)blockIdx.y - 1) * 8 + blockIdx.x;
  const int xcd = g & 7;
  const int r = g >> 3;
  const int mt = xcd * 16 + (r >> 3);  // MT=128, cpx=16
  const int nt = r & 7;
  gemm_tile_body<1, 0>(A, Bt, C, KP, 1024, 1024, mt * 128, nt * 128,
                       nullptr, 0, 0, As, Bs);
}

// ---------------- general MFMA GEMM dispatch (Z2 + knn0) --------------------
template <int BF16OUT, int SWZ, int KNN_PPL, int IND>
__global__ __launch_bounds__(256) void gemm_bt_kernel(const u16* __restrict__ A,
                                                      const u16* __restrict__ Bt,
                                                      void* __restrict__ Cout,
                                                      int K, int ldc, int nvalid,
                                                      const int* __restrict__ find,
                                                      int iNp, int iS,
                                                      const float* __restrict__ kq,
                                                      const float* __restrict__ kr,
                                                      int* __restrict__ kidx,
                                                      int kNp, int kS, int kYoff) {
  const int tid = threadIdx.x;
  const int lane = tid & 63;
  const int wv = tid >> 6;
  if (KNN_PPL > 0 && (int)blockIdx.y >= kYoff) {
    int kb = ((int)blockIdx.y - kYoff) * gridDim.x + blockIdx.x;
    knn_core<KNN_PPL ? KNN_PPL : 1>(kq, kr, kidx, kNp, kS, kb * 4 + wv, lane);
    return;
  }
  __shared__ __align__(16) u16 As[128 * 32];
  __shared__ __align__(16) u16 Bs[128 * 32];
  int mt, nt;
  if (SWZ) {
    const int g = (int)blockIdx.y * gridDim.x + blockIdx.x;
    const int MT = (KNN_PPL > 0 ? kYoff : (int)gridDim.y);
    const int cpx = MT >> 3;
    const int xcd = g & 7;
    const int r = g >> 3;
    mt = xcd * cpx + (r >> 3);
    nt = r & 7;
  } else {
    mt = (int)blockIdx.y;
    nt = blockIdx.x;
  }
  gemm_tile_body<BF16OUT, IND>(A, Bt, Cout, K, ldc, nvalid, mt * 128, nt * 128,
                               find, iNp, iS, As, Bs);
}

// ---------------- stage-1 fused: Z1'(bf16) + Z2'(bf16, indirect) + knn1 -----
// y in [0,32): Z1' tiles (swz MT=32) | y in [32,40): Z2' (IND) | y in [40,72): knn1
__global__ __launch_bounds__(256) void stage1_fused_kernel(const u16* __restrict__ X1bf,
                                                           const u16* __restrict__ Wcomb1,
                                                           const u16* __restrict__ Wa21,
                                                           u16* __restrict__ Z1,
                                                           u16* __restrict__ Z2g,
                                                           const int* __restrict__ fi1,
                                                           const float* __restrict__ npts1,
                                                           const float* __restrict__ npts0,
                                                           int* __restrict__ idx1) {
  __shared__ __align__(16) u16 As[128 * 32];
  __shared__ __align__(16) u16 Bs[128 * 32];
  const int lane = threadIdx.x & 63, wv = threadIdx.x >> 6;
  if (blockIdx.y < 32) {
    const int g = (int)blockIdx.y * 8 + blockIdx.x;
    const int xcd = g & 7;
    const int r = g >> 3;
    const int mt = xcd * 4 + (r >> 3);  // MT=32, cpx=4
    const int nt = r & 7;
    gemm_tile_body<1, 0>(X1bf, Wcomb1, Z1, KP, 1024, 1024, mt * 128, nt * 128,
                         nullptr, 0, 0, As, Bs);
    return;
  }
  if (blockIdx.y < 40) {
    const int mt = (int)blockIdx.y - 32;
    const int nt = blockIdx.x;
    gemm_tile_body<1, 1>(X1bf, Wa21, Z2g, KP, 1024, 1024, mt * 128, nt * 128,
                         fi1, 128, 32, As, Bs);
    return;
  }
  const int kb = ((int)blockIdx.y - 40) * 8 + blockIdx.x;
  knn_core<2>(npts1, npts0, idx1, 128, 32, kb * 4 + wv, lane);
}

// ---------------- fused gather + relu + LN + mean_k -------------------------
// Wave-per-q, DPP add-scan LN, XCD-bijective swizzle. Z1 AND Z2 are bf16
// (exact widening on read); czero fp32. FPS_PPL>0: first 8 blocks run fps.
template <int MODE, int FPS_PPL, int FPS_HS>
__global__ __launch_bounds__(256) void h_epilogue_kernel(const u16* __restrict__ Z1,
                                                         const u16* __restrict__ Z2g,
                                                         const float* __restrict__ czero,
                                                         const int* __restrict__ idxK,
                                                         const int* __restrict__ fi,
                                                         const float* __restrict__ g,
                                                         const float* __restrict__ bb,
                                                         const float* __restrict__ npts,
                                                         void* __restrict__ outp,
                                                         int Np, int S, int cpx,
                                                         const float* __restrict__ fpts,
                                                         int* __restrict__ ffi,
                                                         float* __restrict__ fnpts,
                                                         int fNp, int fS) {
  const int t = threadIdx.x;
  const int lane = t & 63, wv = t >> 6;
  if (FPS_PPL > 0 && blockIdx.x < 8) {
    fps_core<FPS_PPL ? FPS_PPL : 1, FPS_HS>(fpts, ffi, fnpts, fNp, fS,
                                            blockIdx.x * 4 + wv, lane, 0, fS,
                                            nullptr, nullptr);
    return;
  }
  const int bid = blockIdx.x - (FPS_PPL > 0 ? 8 : 0);
  const int sw = (bid & 7) * cpx + (bid >> 3);  // XCD-contiguous q ranges
  const int q = sw * 4 + wv;
  const int b = q / S;
  const int fiv = fi[q];
  const u16* z2 = Z2g + (size_t)q * 1024;
  const u16* zf = Z1 + ((size_t)b * Np + fiv) * 1024;
  const int ch = lane * 4;  // + j*256

  f32x4 base[4], gv[4], bv[4], acc[4];
  #pragma unroll
  for (int j = 0; j < 4; ++j) {
    u16x4 a = *(const u16x4*)(z2 + j * 256 + ch);
    f32x4 c = *(const f32x4*)(czero + j * 256 + ch);
    u16x4 f = *(const u16x4*)(zf + j * 256 + ch);
    #pragma unroll
    for (int c2 = 0; c2 < 4; ++c2) base[j][c2] = bf2f(a[c2]) + c[c2] - bf2f(f[c2]);
    gv[j] = *(const f32x4*)(g + j * 256 + ch);
    bv[j] = *(const f32x4*)(bb + j * 256 + ch);
    #pragma unroll
    for (int c2 = 0; c2 < 4; ++c2) acc[j][c2] = 0.f;
  }
  int nk = 0;
  if (lane < 24) nk = idxK[(size_t)q * 24 + lane];

  for (int k = 0; k < 24; ++k) {
    const int n = __builtin_amdgcn_readlane(nk, k);
    const u16* zr = Z1 + ((size_t)b * Np + n) * 1024;
    f32x4 v[4];
    float s1 = 0.f, s2 = 0.f;
    #pragma unroll
    for (int j = 0; j < 4; ++j) {
      u16x4 r = *(const u16x4*)(zr + j * 256 + ch);
      #pragma unroll
      for (int c2 = 0; c2 < 4; ++c2) {
        float x = fmaxf(bf2f(r[c2]) + base[j][c2], 0.f);
        v[j][c2] = x;
        s1 += x;
        s2 += x * x;
      }
    }
    s1 = wave_sum63(s1);
    s2 = wave_sum63(s2);
    const float S1 = rl_f(s1, 63);
    const float S2 = rl_f(s2, 63);
    const float m = S1 * (1.f / 1024.f);
    const float var = S2 * (1.f / 1024.f) - m * m;
    const float rs = rsqrtf(var + 1e-5f);
    #pragma unroll
    for (int j = 0; j < 4; ++j)
      #pragma unroll
      for (int c2 = 0; c2 < 4; ++c2)
        acc[j][c2] += (v[j][c2] - m) * rs * gv[j][c2] + bv[j][c2];
  }

  u16x4 o4[4];
  #pragma unroll
  for (int j = 0; j < 4; ++j)
    #pragma unroll
    for (int c2 = 0; c2 < 4; ++c2) o4[j][c2] = f2bf(acc[j][c2] * (1.f / 24.f));

  if (MODE == 0) {
    u16* X = (u16*)outp;
    size_t ro = (size_t)q * KP;
    #pragma unroll
    for (int j = 0; j < 4; ++j) *(u16x4*)(X + ro + j * 256 + ch) = o4[j];
    if (lane == 0) {
      X[ro + 1024] = f2bf(npts[(size_t)q * 2]);
      X[ro + 1025] = f2bf(npts[(size_t)q * 2 + 1]);
    }
    if (lane < 15) ((u32*)(X + ro + 1026))[lane] = 0;
  } else {
    u16* X = (u16*)outp + (size_t)q * 1024;
    #pragma unroll
    for (int j = 0; j < 4; ++j) *(u16x4*)(X + j * 256 + ch) = o4[j];
  }
}

// ---------------- MLP MFMA GEMM (fp32 A): P[blk] = W_tile(->bf16) @ Fb^T ----
template <int KSBITS, int NST>
__global__ __launch_bounds__(256, 4) void mlp_mfma_kernel(const float* __restrict__ W,
                                                          const u16* __restrict__ Fb,
                                                          float* __restrict__ P, int K) {
  __shared__ __align__(16) float Asf[128 * 32];
  __shared__ __align__(16) u16 Fsb[32 * 40];
  const int tid = threadIdx.x, lane = tid & 63, wv = tid >> 6;
  const int ot = blockIdx.x >> KSBITS;
  const int ks = blockIdx.x & ((1 << KSBITS) - 1);
  const int m0 = ot * 128;
  const int k0b = ks * (NST * 32);
  const int arow = lane >> 3;
  const int agrp = lane & 7;
  const int rf = lane & 15, quad = lane >> 4;

  f32x4 acc[2][2];
  #pragma unroll
  for (int i = 0; i < 2; ++i)
    #pragma unroll
    for (int j = 0; j < 2; ++j)
      #pragma unroll
      for (int c = 0; c < 4; ++c) acc[i][j][c] = 0.f;

  for (int st = 0; st < NST; ++st) {
    const int k0 = k0b + st * 32;
    #pragma unroll
    for (int i = 0; i < 4; ++i) {
      const int row = wv * 32 + i * 8 + arow;
      const int g = agrp ^ (row & 7);
      const float* ga = W + (size_t)(m0 + row) * K + k0 + g * 4;
      __builtin_amdgcn_global_load_lds((gvp)ga, (svp)(Asf + (wv * 32 + i * 8) * 32), 16, 0, 0);
    }
    if (tid < 128) {
      const int fr = tid >> 2, fc = (tid & 3) * 8;
      u32x4 tmp = *(const u32x4*)(Fb + (size_t)fr * K + k0 + fc);
      *(u32x4*)(Fsb + fr * 40 + fc) = tmp;
    }
    __syncthreads();
    bf16x8 bfr[2];
    #pragma unroll
    for (int ni = 0; ni < 2; ++ni)
      bfr[ni] = *(const bf16x8*)(Fsb + (ni * 16 + rf) * 40 + quad * 8);
    #pragma unroll
    for (int mi = 0; mi < 2; ++mi) {
      const float* ap = Asf + (size_t)(wv * 32 + mi * 16 + rf) * 32;
      f32x4 a0 = *(const f32x4*)(ap + (((quad * 2) ^ (rf & 7)) * 4));
      f32x4 a1 = *(const f32x4*)(ap + (((quad * 2 + 1) ^ (rf & 7)) * 4));
      union { bf16x8 v; u16 h[8]; } af;
      #pragma unroll
      for (int c = 0; c < 4; ++c) { af.h[c] = f2bf(a0[c]); af.h[4 + c] = f2bf(a1[c]); }
      #pragma unroll
      for (int ni = 0; ni < 2; ++ni)
        acc[mi][ni] = __builtin_amdgcn_mfma_f32_16x16x32_bf16(af.v, bfr[ni], acc[mi][ni], 0, 0, 0);
    }
    __syncthreads();
  }

  float* Pb = P + (size_t)blockIdx.x * 4096;
  const int rq = (lane >> 4) * 4, cf = lane & 15;
  #pragma unroll
  for (int mi = 0; mi < 2; ++mi)
    #pragma unroll
    for (int ni = 0; ni < 2; ++ni)
      #pragma unroll
      for (int r = 0; r < 4; ++r)
        Pb[(wv * 32 + mi * 16 + rq + r) * 32 + ni * 16 + cf] = acc[mi][ni][r];
}

// ---------------- K-split partial reductions (bias fused) -------------------
__global__ __launch_bounds__(256) void reduce_flat_kernel(const float* __restrict__ P,
                                                          const float* __restrict__ bias,
                                                          u16* __restrict__ x1bf) {
  int idx = blockIdx.x * 256 + threadIdx.x;  // 32768
  int o = idx >> 5, b = idx & 31;
  float s = bias[o];
  const float* p = P + ((size_t)(o >> 7) * 64) * 4096 + (o & 127) * 32 + b;
  #pragma unroll 8
  for (int ks = 0; ks < 64; ++ks) s += p[(size_t)ks * 4096];
  x1bf[(size_t)b * 1024 + o] = f2bf(s);
}

__global__ __launch_bounds__(256) void reduce_dim_kernel(const float* __restrict__ P,
                                                         const float* __restrict__ bias,
                                                         float* __restrict__ out) {
  int idx = blockIdx.x * 256 + threadIdx.x;  // 131072
  int o = idx >> 5, b = idx & 31;
  float s = bias[o];
  const float* p = P + ((size_t)(o >> 7) * 8) * 4096 + (o & 127) * 32 + b;
  #pragma unroll
  for (int ks = 0; ks < 8; ++ks) s += p[(size_t)ks * 4096];
  out[(size_t)b * 4096 + o] = s;
}

// ---------------------------------------------------------------------------
extern "C" void kernel_launch(void* const* d_in, const int* in_sizes, int n_in,
                              void* d_out, int out_size, void* d_ws, size_t ws_size,
                              hipStream_t stream) {
  const float* fmap  = (const float*)d_in[0];
  const float* pts   = (const float*)d_in[1];
  const float* Wdiff = (const float*)d_in[2];
  const float* bdiff = (const float*)d_in[3];
  const float* Wagg  = (const float*)d_in[4];
  const float* bagg  = (const float*)d_in[5];
  const float* lng   = (const float*)d_in[6];
  const float* lnb   = (const float*)d_in[7];
  const float* Wflat = (const float*)d_in[8];
  const float* bflat = (const float*)d_in[9];
  const float* Wdim  = (const float*)d_in[10];
  const float* bdim  = (const float*)d_in[11];
  float* out = (float*)d_out;

  char* w = (char*)d_ws;
  size_t off = 0;
  auto alloc = [&](size_t n) { char* p = w + off; off += (n + 255) & ~(size_t)255; return p; };

  u16* Z1    = (u16*)alloc(16384ull * 1024 * 2);      // 33.5 MB bf16
  u16* Z2g   = (u16*)alloc(4096ull * 1024 * 2);       // 8.4 MB bf16
  u16* Xbf0  = (u16*)alloc(16384ull * KP * 2);
  u16* X1bf  = (u16*)alloc(4096ull * KP * 2);
  u16* WdT   = (u16*)alloc(2ull * NP0 * KP * 2);      // both stages
  u16* Wa1   = (u16*)alloc(2ull * 1024 * KP * 2);
  u16* Wa2   = (u16*)alloc(2ull * 1024 * KP * 2);
  u16* Wcomb = (u16*)alloc(2ull * 1024 * KP * 2);
  float* czero = (float*)alloc(2 * 1024 * 4);
  int* fi0   = (int*)alloc(32 * 128 * 4);
  int* fi1   = (int*)alloc(32 * 32 * 4);
  int* idx0  = (int*)alloc(32 * 128 * 24 * 4);
  int* idx1  = (int*)alloc(32 * 32 * 24 * 4);
  float* npts0 = (float*)alloc(32 * 128 * 2 * 4);
  float* npts1 = (float*)alloc(32 * 32 * 2 * 4);
  u16* fea2bf = (u16*)alloc(32ull * 32768 * 2);       // 2 MB bf16
  u16* x1bf   = (u16*)alloc(32ull * 1024 * 2);        // 64 KB bf16
  float* Pf   = (float*)alloc(512ull * 4096 * 4);     // 8 MB partials (flat)
  float* Pd   = (float*)alloc(256ull * 4096 * 4);     // 4 MB partials (dim)
  float* fdist = (float*)alloc(32ull * 512 * 4);      // fps0 dist state
  int* ffar    = (int*)alloc(32 * 4);                 // fps0 far state

  // D1: stage-0 inputs + fps0 [0,32)
  bilinear_fused_kernel<<<dim3(32, 33), 256, 0, stream>>>(fmap, pts, Xbf0, fi0, npts0,
                                                          fdist, ffar);
  // D2: merged weight prep (both stages) + fps0 [32,56)
  prep_merged_kernel<<<4432, 256, 0, stream>>>(Wdiff, WdT, Wagg, bdiff, bagg,
                                               Wa1, Wa2, czero, pts, fi0, npts0,
                                               fdist, ffar);
  // D3: both Wcomb GEMMs + fps0 [56,78)
  wcomb_dual_kernel<<<dim3(9, 17), 256, 0, stream>>>(Wa1, WdT, Wcomb, pts, fi0, npts0,
                                                     fdist, ffar);
  // D4: Z1 (stage0, bf16 out) + fps0 [78,128)
  z1_fused_kernel<<<dim3(8, 129), 256, 0, stream>>>(Xbf0, Wcomb, Z1,
                                                    pts, fi0, npts0, fdist, ffar);
  // D5: Z2 (bf16 out, A rows via fi0) + knn0
  gemm_bt_kernel<1, 1, 8, 1><<<dim3(8, 160), 256, 0, stream>>>(
      Xbf0, Wa2, Z2g, KP, 1024, 1024,
      fi0, 512, 128,
      npts0, pts, idx0, 512, 128, 32);
  // D6: h_epilogue0 + fps1 full [0,32)
  h_epilogue_kernel<0, 2, 1><<<1032, 256, 0, stream>>>(
      Z1, Z2g, czero, idx0, fi0, lng, lnb, npts0, X1bf, 512, 128, 128,
      npts0, fi1, npts1, 128, 32);
  // D7: stage-1 fused (Z1'(bf16) + Z2'(bf16) + knn1)
  stage1_fused_kernel<<<dim3(8, 72), 256, 0, stream>>>(
      X1bf, Wcomb + 1024ull * KP, Wa2 + 1024ull * KP, Z1, Z2g, fi1,
      npts1, npts0, idx1);
  // D8: h_epilogue1
  h_epilogue_kernel<1, 0, 1><<<256, 256, 0, stream>>>(
      Z1, Z2g, czero + 1024, idx1, fi1, lng + 1024, lnb + 1024, npts1, fea2bf,
      128, 32, 32, nullptr, nullptr, nullptr, 0, 0);

  // D9-12: final MLP (MFMA, K-split partials + reduce)
  mlp_mfma_kernel<6, 16><<<512, 256, 0, stream>>>(Wflat, fea2bf, Pf, 32768);
  reduce_flat_kernel<<<128, 256, 0, stream>>>(Pf, bflat, x1bf);
  mlp_mfma_kernel<3, 4><<<256, 256, 0, stream>>>(Wdim, x1bf, Pd, 1024);
  reduce_dim_kernel<<<512, 256, 0, stream>>>(Pd, bdim, out);
}